// Round 1
// baseline (576.999 us; speedup 1.0000x reference)
//
#include <hip/hip_runtime.h>
#include <hip/hip_bf16.h>
#include <math.h>

typedef __bf16 bf16_t;
typedef __bf16 bf16x4 __attribute__((ext_vector_type(4)));
typedef __bf16 bf16x8 __attribute__((ext_vector_type(8)));
typedef float  f32x4  __attribute__((ext_vector_type(4)));

#define MFMA16(a,b,c) __builtin_amdgcn_mfma_f32_16x16x32_bf16((a),(b),(c),0,0,0)

// Problem constants
#define B_ 2
#define L_ 2048
#define D_ 2048
#define H_ 16
#define KV_ 4
#define E_ 128
#define M_ (B_*L_)      // 4096 rows
#define NQKV_ 3072      // H*E + 2*KV*E

// ---------------------------------------------------------------- cast x -> bf16
__global__ __launch_bounds__(256) void cast_bf16_kernel(const float* __restrict__ src,
                                                        bf16_t* __restrict__ dst, int n) {
    int i = (blockIdx.x * 256 + threadIdx.x) * 4;
    if (i < n) {
        float4 v = *(const float4*)(src + i);
        bf16x4 o;
        o.x = (bf16_t)v.x; o.y = (bf16_t)v.y; o.z = (bf16_t)v.z; o.w = (bf16_t)v.w;
        *(bf16x4*)(dst + i) = o;
    }
}

// -------------------------------------------- transpose + cast: W[K,N] f32 -> WT[N,K] bf16
__global__ __launch_bounds__(256) void transpose_cast_kernel(const float* __restrict__ W,
                                                             bf16_t* __restrict__ WT,
                                                             int K, int N) {
    __shared__ float tile[32][33];
    int n0 = blockIdx.x * 32, k0 = blockIdx.y * 32;
    int tx = threadIdx.x, ty = threadIdx.y;  // 32 x 8
    #pragma unroll
    for (int i = 0; i < 32; i += 8)
        tile[ty + i][tx] = W[(size_t)(k0 + ty + i) * N + n0 + tx];
    __syncthreads();
    #pragma unroll
    for (int i = 0; i < 32; i += 8)
        WT[(size_t)(n0 + ty + i) * K + k0 + tx] = (bf16_t)tile[tx][ty + i];
}

// ---------------------------------------------------------------- concat qkv bias
__global__ void concat_bias_kernel(const float* __restrict__ bq, const float* __restrict__ bk,
                                   const float* __restrict__ bv, float* __restrict__ out) {
    int i = blockIdx.x * 256 + threadIdx.x;
    if (i < 2048) out[i] = bq[i];
    else if (i < 2560) out[i] = bk[i - 2048];
    else if (i < 3072) out[i] = bv[i - 2560];
}

// -------------------------------- V transpose: QKV[b,l,2560+kv*128+e] -> Vt[(b*4+kv)*128+e][l]
__global__ __launch_bounds__(256) void transpose_v_kernel(const bf16_t* __restrict__ QKV,
                                                          bf16_t* __restrict__ Vt) {
    __shared__ bf16_t tile[32][33];
    int e0 = blockIdx.x * 32, l0 = blockIdx.y * 32;
    int bk = blockIdx.z;                    // b*4 + kv
    int b = bk >> 2, kv = bk & 3;
    int tx = threadIdx.x, ty = threadIdx.y; // 32 x 8
    #pragma unroll
    for (int i = 0; i < 32; i += 8)
        tile[ty + i][tx] = QKV[(size_t)(b * L_ + l0 + ty + i) * NQKV_ + 2560 + kv * 128 + e0 + tx];
    __syncthreads();
    #pragma unroll
    for (int i = 0; i < 32; i += 8)
        Vt[((size_t)bk * 128 + e0 + ty + i) * L_ + l0 + tx] = tile[tx][ty + i];
}

// ---------------------------------------------------------------- bf16 MFMA GEMM
// C[M,N] = A[M,K] @ BT[N,K]^T + bias ; 128x128 tile, 4 waves, 4x4 16x16x32 MFMAs/wave
template <bool OUT_BF16>
__global__ __launch_bounds__(256) void gemm_kernel(const bf16_t* __restrict__ A,
                                                   const bf16_t* __restrict__ BT,
                                                   const float* __restrict__ bias,
                                                   void* __restrict__ C,
                                                   int M, int N, int K) {
    __shared__ __align__(16) bf16_t sA[128][32];
    __shared__ __align__(16) bf16_t sB[128][32];
    int tid = threadIdx.x;
    int wave = tid >> 6, lane = tid & 63;
    int l16 = lane & 15, quad = lane >> 4;
    int row0 = blockIdx.y * 128;
    int col0 = blockIdx.x * 128;
    int wm = (wave >> 1) * 64;
    int wn = (wave & 1) * 64;

    f32x4 acc[4][4];
    #pragma unroll
    for (int i = 0; i < 4; ++i)
        #pragma unroll
        for (int j = 0; j < 4; ++j)
            acc[i][j] = f32x4{0.f, 0.f, 0.f, 0.f};

    for (int k0 = 0; k0 < K; k0 += 32) {
        #pragma unroll
        for (int c = 0; c < 2; ++c) {
            int lin = (c * 256 + tid) * 8;
            int r = lin >> 5, col = lin & 31;
            *(bf16x8*)&sA[r][col] = *(const bf16x8*)&A[(size_t)(row0 + r) * K + k0 + col];
            *(bf16x8*)&sB[r][col] = *(const bf16x8*)&BT[(size_t)(col0 + r) * K + k0 + col];
        }
        __syncthreads();
        bf16x8 af[4], bf[4];
        #pragma unroll
        for (int mt = 0; mt < 4; ++mt) af[mt] = *(const bf16x8*)&sA[wm + mt * 16 + l16][quad * 8];
        #pragma unroll
        for (int nt = 0; nt < 4; ++nt) bf[nt] = *(const bf16x8*)&sB[wn + nt * 16 + l16][quad * 8];
        #pragma unroll
        for (int mt = 0; mt < 4; ++mt)
            #pragma unroll
            for (int nt = 0; nt < 4; ++nt)
                acc[mt][nt] = MFMA16(af[mt], bf[nt], acc[mt][nt]);
        __syncthreads();
    }

    #pragma unroll
    for (int mt = 0; mt < 4; ++mt) {
        #pragma unroll
        for (int nt = 0; nt < 4; ++nt) {
            int gcol = col0 + wn + nt * 16 + l16;
            float bv = bias[gcol];
            #pragma unroll
            for (int r = 0; r < 4; ++r) {
                int grow = row0 + wm + mt * 16 + quad * 4 + r;
                float v = acc[mt][nt][r] + bv;
                if (OUT_BF16) ((bf16_t*)C)[(size_t)grow * N + gcol] = (bf16_t)v;
                else          ((float*)C)[(size_t)grow * N + gcol] = v;
            }
        }
    }
}

// ---------------------------------------------------------------- flash attention (causal GQA)
// grid: B*H*(L/64); block 256 = 4 waves; wave w owns 16 q-rows
__global__ __launch_bounds__(256) void attn_kernel(const bf16_t* __restrict__ QKV,
                                                   const bf16_t* __restrict__ Vt,
                                                   bf16_t* __restrict__ Ctx) {
    __shared__ __align__(16) bf16_t sK[32][128];   // [k within tile][e]
    __shared__ __align__(16) bf16_t sV[128][32];   // [e][k within tile]  (from Vt)
    __shared__ __align__(16) bf16_t sP[4][16][40]; // per-wave P round-trip, stride 40 (16B-aligned rows)

    int tid = threadIdx.x;
    int wave = tid >> 6, lane = tid & 63;
    int l16 = lane & 15, quad = lane >> 4;
    int blk = blockIdx.x;
    int qt = blk & 31;
    int h  = (blk >> 5) & 15;
    int b  = blk >> 9;
    int kv = h & 3;
    int q0 = qt * 64;
    int qbase = q0 + wave * 16;

    // Q fragments (A-operand layout): 4 e-tiles of K=32
    bf16x8 aq[4];
    #pragma unroll
    for (int et = 0; et < 4; ++et)
        aq[et] = *(const bf16x8*)&QKV[(size_t)(b * L_ + qbase + l16) * NQKV_ + h * 128 + et * 32 + quad * 8];

    f32x4 acc[8];
    #pragma unroll
    for (int i = 0; i < 8; ++i) acc[i] = f32x4{0.f, 0.f, 0.f, 0.f};
    float m_i[4], l_i[4];
    #pragma unroll
    for (int r = 0; r < 4; ++r) { m_i[r] = -3.0e38f; l_i[r] = 0.f; }

    const bf16_t* Kbase = QKV + (size_t)(b * L_) * NQKV_ + 2048 + kv * 128;
    const bf16_t* Vbase = Vt + (size_t)(b * 4 + kv) * 128 * L_;
    const float scale = 0.08838834764831845f; // 1/sqrt(128)

    int ktiles = (q0 >> 5) + 2;
    for (int kt = 0; kt < ktiles; ++kt) {
        int kk0 = kt * 32;
        #pragma unroll
        for (int c = 0; c < 2; ++c) {
            int lin = (c * 256 + tid) * 8;
            { int r = lin >> 7, col = lin & 127;
              *(bf16x8*)&sK[r][col] = *(const bf16x8*)&Kbase[(size_t)(kk0 + r) * NQKV_ + col]; }
            { int r = lin >> 5, col = lin & 31;
              *(bf16x8*)&sV[r][col] = *(const bf16x8*)&Vbase[(size_t)r * L_ + kk0 + col]; }
        }
        __syncthreads();

        // S = Q K^T  (two 16-col tiles)
        f32x4 s[2];
        s[0] = f32x4{0.f,0.f,0.f,0.f}; s[1] = f32x4{0.f,0.f,0.f,0.f};
        #pragma unroll
        for (int c = 0; c < 2; ++c)
            #pragma unroll
            for (int et = 0; et < 4; ++et) {
                bf16x8 bk_ = *(const bf16x8*)&sK[c * 16 + l16][et * 32 + quad * 8];
                s[c] = MFMA16(aq[et], bk_, s[c]);
            }

        // scale + causal mask
        #pragma unroll
        for (int c = 0; c < 2; ++c) {
            int kidx = kk0 + c * 16 + l16;
            #pragma unroll
            for (int r = 0; r < 4; ++r) {
                int qidx = qbase + quad * 4 + r;
                float v = s[c][r] * scale;
                s[c][r] = (kidx <= qidx) ? v : -3.0e38f;
            }
        }

        // online softmax update (row stats across 16 lanes of the quad)
        float alpha[4];
        #pragma unroll
        for (int r = 0; r < 4; ++r) {
            float mx = fmaxf(s[0][r], s[1][r]);
            #pragma unroll
            for (int off = 1; off < 16; off <<= 1) mx = fmaxf(mx, __shfl_xor(mx, off, 64));
            float mnew = fmaxf(m_i[r], mx);
            alpha[r] = __expf(m_i[r] - mnew);
            s[0][r] = __expf(s[0][r] - mnew);
            s[1][r] = __expf(s[1][r] - mnew);
            float rs = s[0][r] + s[1][r];
            #pragma unroll
            for (int off = 1; off < 16; off <<= 1) rs += __shfl_xor(rs, off, 64);
            l_i[r] = l_i[r] * alpha[r] + rs;
            m_i[r] = mnew;
        }
        #pragma unroll
        for (int nt = 0; nt < 8; ++nt)
            #pragma unroll
            for (int r = 0; r < 4; ++r) acc[nt][r] *= alpha[r];

        // P -> LDS (C/D layout in, A layout out)
        #pragma unroll
        for (int c = 0; c < 2; ++c)
            #pragma unroll
            for (int r = 0; r < 4; ++r)
                sP[wave][quad * 4 + r][c * 16 + l16] = (bf16_t)s[c][r];
        asm volatile("s_waitcnt lgkmcnt(0)" ::: "memory");

        bf16x8 ap = *(const bf16x8*)&sP[wave][l16][quad * 8];
        #pragma unroll
        for (int nt = 0; nt < 8; ++nt) {
            bf16x8 bv = *(const bf16x8*)&sV[nt * 16 + l16][quad * 8];
            acc[nt] = MFMA16(ap, bv, acc[nt]);
        }
        __syncthreads();
    }

    // epilogue: ctx = acc / l
    #pragma unroll
    for (int nt = 0; nt < 8; ++nt)
        #pragma unroll
        for (int r = 0; r < 4; ++r) {
            int grow = qbase + quad * 4 + r;
            float v = acc[nt][r] / l_i[r];
            Ctx[(size_t)(b * L_ + grow) * 2048 + h * 128 + nt * 16 + l16] = (bf16_t)v;
        }
}

// ------------------------------------------ GELU(erf) + residual + LayerNorm, one row/block
__global__ __launch_bounds__(256) void ln_kernel(const float* __restrict__ Y,
                                                 const float* __restrict__ X,
                                                 const float* __restrict__ gamma,
                                                 const float* __restrict__ beta,
                                                 float* __restrict__ out) {
    __shared__ float sr[2048];
    __shared__ float wred[8];
    size_t row = blockIdx.x;
    const float* y = Y + row * 2048;
    const float* x = X + row * 2048;
    float sum = 0.f, ssq = 0.f;
    #pragma unroll
    for (int c = 0; c < 2; ++c) {
        int i = (c * 256 + threadIdx.x) * 4;
        float4 yv = *(const float4*)(y + i);
        float4 xv = *(const float4*)(x + i);
        float r0 = xv.x + 0.5f * yv.x * (1.f + erff(yv.x * 0.70710678118654752f));
        float r1 = xv.y + 0.5f * yv.y * (1.f + erff(yv.y * 0.70710678118654752f));
        float r2 = xv.z + 0.5f * yv.z * (1.f + erff(yv.z * 0.70710678118654752f));
        float r3 = xv.w + 0.5f * yv.w * (1.f + erff(yv.w * 0.70710678118654752f));
        sr[i] = r0; sr[i + 1] = r1; sr[i + 2] = r2; sr[i + 3] = r3;
        sum += r0 + r1 + r2 + r3;
        ssq += r0 * r0 + r1 * r1 + r2 * r2 + r3 * r3;
    }
    #pragma unroll
    for (int off = 32; off > 0; off >>= 1) {
        sum += __shfl_xor(sum, off, 64);
        ssq += __shfl_xor(ssq, off, 64);
    }
    int wv = threadIdx.x >> 6;
    if ((threadIdx.x & 63) == 0) { wred[wv] = sum; wred[wv + 4] = ssq; }
    __syncthreads();
    sum = wred[0] + wred[1] + wred[2] + wred[3];
    ssq = wred[4] + wred[5] + wred[6] + wred[7];
    float mu = sum * (1.f / 2048.f);
    float var = ssq * (1.f / 2048.f) - mu * mu;
    float rstd = rsqrtf(var + 1e-5f);
    #pragma unroll
    for (int c = 0; c < 2; ++c) {
        int i = (c * 256 + threadIdx.x) * 4;
        float4 gv = *(const float4*)(gamma + i);
        float4 bv = *(const float4*)(beta + i);
        float4 o;
        o.x = (sr[i]     - mu) * rstd * gv.x + bv.x;
        o.y = (sr[i + 1] - mu) * rstd * gv.y + bv.y;
        o.z = (sr[i + 2] - mu) * rstd * gv.z + bv.z;
        o.w = (sr[i + 3] - mu) * rstd * gv.w + bv.w;
        *(float4*)(out + row * 2048 + i) = o;
    }
}

// ----------------------------------------------------------------------------- launch
extern "C" void kernel_launch(void* const* d_in, const int* in_sizes, int n_in,
                              void* d_out, int out_size, void* d_ws, size_t ws_size,
                              hipStream_t stream) {
    const float* x     = (const float*)d_in[0];
    const float* Wq    = (const float*)d_in[1];
    const float* bq    = (const float*)d_in[2];
    const float* Wk    = (const float*)d_in[3];
    const float* bk    = (const float*)d_in[4];
    const float* Wv    = (const float*)d_in[5];
    const float* bv    = (const float*)d_in[6];
    const float* Wo    = (const float*)d_in[7];
    const float* bo    = (const float*)d_in[8];
    const float* gamma = (const float*)d_in[9];
    const float* beta  = (const float*)d_in[10];
    float* out = (float*)d_out;

    char* ws = (char*)d_ws;
    size_t off = 0;
    bf16_t* xb    = (bf16_t*)(ws + off); off += 16777216;   // 4096x2048 bf16
    bf16_t* WqkvT = (bf16_t*)(ws + off); off += 12582912;   // 3072x2048 bf16
    bf16_t* WoT   = (bf16_t*)(ws + off); off += 8388608;    // 2048x2048 bf16
    float*  qbias = (float*)(ws + off);  off += 12288;      // 3072 f32
    bf16_t* QKV   = (bf16_t*)(ws + off); off += 25165824;   // 4096x3072 bf16
    bf16_t* Vt    = (bf16_t*)(ws + off); off += 4194304;    // 8x128x2048 bf16
    bf16_t* Cb    = (bf16_t*)(ws + off); off += 16777216;   // 4096x2048 bf16
    float*  Yb    = (float*)(ws + off);  off += 33554432;   // 4096x2048 f32

    cast_bf16_kernel<<<8192, 256, 0, stream>>>(x, xb, M_ * D_);
    transpose_cast_kernel<<<dim3(64, 64), dim3(32, 8), 0, stream>>>(Wq, WqkvT, 2048, 2048);
    transpose_cast_kernel<<<dim3(16, 64), dim3(32, 8), 0, stream>>>(Wk, WqkvT + 2048 * 2048, 2048, 512);
    transpose_cast_kernel<<<dim3(16, 64), dim3(32, 8), 0, stream>>>(Wv, WqkvT + 2560 * 2048, 2048, 512);
    transpose_cast_kernel<<<dim3(64, 64), dim3(32, 8), 0, stream>>>(Wo, WoT, 2048, 2048);
    concat_bias_kernel<<<12, 256, 0, stream>>>(bq, bk, bv, qbias);

    gemm_kernel<true><<<dim3(24, 32), 256, 0, stream>>>(xb, WqkvT, qbias, QKV, M_, NQKV_, D_);
    transpose_v_kernel<<<dim3(4, 64, 8), dim3(32, 8), 0, stream>>>(QKV, Vt);
    attn_kernel<<<B_ * H_ * (L_ / 64), 256, 0, stream>>>(QKV, Vt, Cb);
    gemm_kernel<false><<<dim3(16, 32), 256, 0, stream>>>(Cb, WoT, bo, Yb, M_, D_, 2048);
    ln_kernel<<<M_, 256, 0, stream>>>(Yb, x, gamma, beta, out);
}

// Round 2
// 506.529 us; speedup vs baseline: 1.1391x; 1.1391x over previous
//
#include <hip/hip_runtime.h>
#include <hip/hip_bf16.h>
#include <math.h>

typedef __bf16 bf16_t;
typedef __bf16 bf16x4 __attribute__((ext_vector_type(4)));
typedef __bf16 bf16x8 __attribute__((ext_vector_type(8)));
typedef float  f32x4  __attribute__((ext_vector_type(4)));
typedef float  f32x16 __attribute__((ext_vector_type(16)));

#define MFMA16(a,b,c) __builtin_amdgcn_mfma_f32_16x16x32_bf16((a),(b),(c),0,0,0)
#define MFMA32(a,b,c) __builtin_amdgcn_mfma_f32_32x32x16_bf16((a),(b),(c),0,0,0)

// Problem constants
#define B_ 2
#define L_ 2048
#define D_ 2048
#define H_ 16
#define KV_ 4
#define E_ 128
#define M_ (B_*L_)      // 4096 rows
#define NQKV_ 3072      // H*E + 2*KV*E

// async global->LDS 16B (m97 pattern; LDS side must be wave-uniform base + lane*16)
__device__ __forceinline__ void async_ld16(const bf16_t* g, bf16_t* l) {
    __builtin_amdgcn_global_load_lds((const __attribute__((address_space(1))) void*)g,
                                     (__attribute__((address_space(3))) void*)l, 16, 0, 0);
}

// ---------------------------------------------------------------- cast x -> bf16
__global__ __launch_bounds__(256) void cast_bf16_kernel(const float* __restrict__ src,
                                                        bf16_t* __restrict__ dst, int n) {
    int i = (blockIdx.x * 256 + threadIdx.x) * 4;
    if (i < n) {
        float4 v = *(const float4*)(src + i);
        bf16x4 o;
        o.x = (bf16_t)v.x; o.y = (bf16_t)v.y; o.z = (bf16_t)v.z; o.w = (bf16_t)v.w;
        *(bf16x4*)(dst + i) = o;
    }
}

// -------------------------------------------- transpose + cast: W[K,N] f32 -> WT[N,K] bf16
__global__ __launch_bounds__(256) void transpose_cast_kernel(const float* __restrict__ W,
                                                             bf16_t* __restrict__ WT,
                                                             int K, int N) {
    __shared__ float tile[32][33];
    int n0 = blockIdx.x * 32, k0 = blockIdx.y * 32;
    int tx = threadIdx.x, ty = threadIdx.y;  // 32 x 8
    #pragma unroll
    for (int i = 0; i < 32; i += 8)
        tile[ty + i][tx] = W[(size_t)(k0 + ty + i) * N + n0 + tx];
    __syncthreads();
    #pragma unroll
    for (int i = 0; i < 32; i += 8)
        WT[(size_t)(n0 + ty + i) * K + k0 + tx] = (bf16_t)tile[tx][ty + i];
}

// ---------------------------------------------------------------- concat qkv bias
__global__ void concat_bias_kernel(const float* __restrict__ bq, const float* __restrict__ bk,
                                   const float* __restrict__ bv, float* __restrict__ out) {
    int i = blockIdx.x * 256 + threadIdx.x;
    if (i < 2048) out[i] = bq[i];
    else if (i < 2560) out[i] = bk[i - 2048];
    else if (i < 3072) out[i] = bv[i - 2560];
}

// -------------------------------- V transpose: QKV[b,l,2560+kv*128+e] -> Vt[(b*4+kv)*128+e][l]
__global__ __launch_bounds__(256) void transpose_v_kernel(const bf16_t* __restrict__ QKV,
                                                          bf16_t* __restrict__ Vt) {
    __shared__ bf16_t tile[32][33];
    int e0 = blockIdx.x * 32, l0 = blockIdx.y * 32;
    int bk = blockIdx.z;                    // b*4 + kv
    int b = bk >> 2, kv = bk & 3;
    int tx = threadIdx.x, ty = threadIdx.y; // 32 x 8
    #pragma unroll
    for (int i = 0; i < 32; i += 8)
        tile[ty + i][tx] = QKV[(size_t)(b * L_ + l0 + ty + i) * NQKV_ + 2560 + kv * 128 + e0 + tx];
    __syncthreads();
    #pragma unroll
    for (int i = 0; i < 32; i += 8)
        Vt[((size_t)bk * 128 + e0 + ty + i) * L_ + l0 + tx] = tile[tx][ty + i];
}

// ---------------------------------------------------------------- bf16 MFMA GEMM
// C[M,N] = A[M,K] @ BT[N,K]^T + bias ; 128x128 tile, 4 waves, 4x4 16x16x32 MFMAs/wave
// staging via global_load_lds width 16 (m97)
template <bool OUT_BF16>
__global__ __launch_bounds__(256) void gemm_kernel(const bf16_t* __restrict__ A,
                                                   const bf16_t* __restrict__ BT,
                                                   const float* __restrict__ bias,
                                                   void* __restrict__ C,
                                                   int M, int N, int K) {
    __shared__ __align__(16) bf16_t sA[128][32];
    __shared__ __align__(16) bf16_t sB[128][32];
    int tid = threadIdx.x;
    int wave = tid >> 6, lane = tid & 63;
    int l16 = lane & 15, quad = lane >> 4;
    int row0 = blockIdx.y * 128;
    int col0 = blockIdx.x * 128;
    int wm = (wave >> 1) * 64;
    int wn = (wave & 1) * 64;

    f32x4 acc[4][4];
    #pragma unroll
    for (int i = 0; i < 4; ++i)
        #pragma unroll
        for (int j = 0; j < 4; ++j)
            acc[i][j] = f32x4{0.f, 0.f, 0.f, 0.f};

    for (int k0 = 0; k0 < K; k0 += 32) {
        #pragma unroll
        for (int c = 0; c < 2; ++c) {
            int lin = (c * 256 + tid) * 8;
            int r = lin >> 5, col = lin & 31;
            async_ld16(&A[(size_t)(row0 + r) * K + k0 + col], &sA[r][col]);
            async_ld16(&BT[(size_t)(col0 + r) * K + k0 + col], &sB[r][col]);
        }
        __syncthreads();
        bf16x8 af[4], bf[4];
        #pragma unroll
        for (int mt = 0; mt < 4; ++mt) af[mt] = *(const bf16x8*)&sA[wm + mt * 16 + l16][quad * 8];
        #pragma unroll
        for (int nt = 0; nt < 4; ++nt) bf[nt] = *(const bf16x8*)&sB[wn + nt * 16 + l16][quad * 8];
        #pragma unroll
        for (int mt = 0; mt < 4; ++mt)
            #pragma unroll
            for (int nt = 0; nt < 4; ++nt)
                acc[mt][nt] = MFMA16(af[mt], bf[nt], acc[mt][nt]);
        __syncthreads();
    }

    #pragma unroll
    for (int mt = 0; mt < 4; ++mt) {
        #pragma unroll
        for (int nt = 0; nt < 4; ++nt) {
            int gcol = col0 + wn + nt * 16 + l16;
            float bv = bias[gcol];
            #pragma unroll
            for (int r = 0; r < 4; ++r) {
                int grow = row0 + wm + mt * 16 + quad * 4 + r;
                float v = acc[mt][nt][r] + bv;
                if (OUT_BF16) ((bf16_t*)C)[(size_t)grow * N + gcol] = (bf16_t)v;
                else          ((float*)C)[(size_t)grow * N + gcol] = v;
            }
        }
    }
}

// ---------------------------------------------------------------- flash attention (causal GQA)
// S^T = K@Q^T and ctx^T = V^T@P trick: softmax row-dim lands in registers (1 shfl per
// reduction) and alpha/l live in the same lane (col=q=lane&31) for both S^T and ctx^T.
// BK=64 kpos/iter, 32 q/wave, 2 waves/block (64 q-rows), block does paired tiles
// (t, 31-t) -> constant 33 iters/block; grid 512 = 2 blocks/CU.
__global__ __launch_bounds__(128) void attn_kernel(const bf16_t* __restrict__ QKV,
                                                   const bf16_t* __restrict__ Vt,
                                                   bf16_t* __restrict__ Ctx) {
    __shared__ __align__(16) bf16_t sK[64][136];    // [kpos][e] pad->4-bank shift/row
    __shared__ __align__(16) bf16_t sV[128][72];    // [e][kpos]
    __shared__ __align__(16) bf16_t sP[2][32][72];  // per-wave P^T round-trip [q][kpos]

    const int tid = threadIdx.x;
    const int wave = tid >> 6, lane = tid & 63;
    const int l31 = lane & 31, half = lane >> 5;
    const int pair = blockIdx.x & 15;
    const int h = (blockIdx.x >> 4) & 15;
    const int b = blockIdx.x >> 8;
    const int kv = h & 3;

    const bf16_t* Kbase = QKV + (size_t)b * L_ * NQKV_ + 2048 + kv * 128;
    const bf16_t* Vbase = Vt + (size_t)(b * 4 + kv) * 128 * L_;
    const float scale = 0.08838834764831845f; // 1/sqrt(128)

    for (int phase = 0; phase < 2; ++phase) {
        const int t = phase ? 31 - pair : pair;
        const int q0 = t * 64;
        const int qrow = q0 + wave * 32 + l31;   // this lane's q row (stats + B-frag n)

        // Q fragments (B-operand: n=q=l31, k=e)
        bf16x8 qf[8];
        const bf16_t* Qrow = QKV + (size_t)(b * L_ + qrow) * NQKV_ + h * 128 + half * 8;
        #pragma unroll
        for (int et = 0; et < 8; ++et) qf[et] = *(const bf16x8*)&Qrow[et * 16];

        f32x16 acc[4];
        #pragma unroll
        for (int em = 0; em < 4; ++em)
            #pragma unroll
            for (int j = 0; j < 16; ++j) acc[em][j] = 0.f;
        float m_i = -3.0e38f, l_i = 0.f;

        for (int kt = 0; kt <= t; ++kt) {
            const int kk0 = kt * 64;
            // stage K[64x128] and V^T[128x64]
            #pragma unroll
            for (int p = 0; p < 8; ++p) {
                int lin = (p * 128 + tid) * 8;
                { int r = lin >> 7, c = lin & 127;
                  *(bf16x8*)&sK[r][c] = *(const bf16x8*)&Kbase[(size_t)(kk0 + r) * NQKV_ + c]; }
                { int r = lin >> 6, c = lin & 63;
                  *(bf16x8*)&sV[r][c] = *(const bf16x8*)&Vbase[(size_t)r * L_ + kk0 + c]; }
            }
            __syncthreads();

            // S^T[kpos][q] = K @ Q^T  (2 kpos-mtiles x 8 e-ktiles)
            f32x16 s[2];
            #pragma unroll
            for (int mt = 0; mt < 2; ++mt)
                #pragma unroll
                for (int j = 0; j < 16; ++j) s[mt][j] = 0.f;
            #pragma unroll
            for (int mt = 0; mt < 2; ++mt)
                #pragma unroll
                for (int et = 0; et < 8; ++et) {
                    bf16x8 kf = *(const bf16x8*)&sK[mt * 32 + l31][et * 16 + half * 8];
                    s[mt] = MFMA32(kf, qf[et], s[mt]);
                }

            #pragma unroll
            for (int mt = 0; mt < 2; ++mt)
                #pragma unroll
                for (int j = 0; j < 16; ++j) s[mt][j] *= scale;

            // causal mask: only the diagonal tile needs it (kpos row = (j&3)+8*(j>>2)+4*half)
            if (kt == t) {
                #pragma unroll
                for (int mt = 0; mt < 2; ++mt)
                    #pragma unroll
                    for (int j = 0; j < 16; ++j) {
                        int kidx = kk0 + mt * 32 + (j & 3) + 8 * (j >> 2) + 4 * half;
                        if (kidx > qrow) s[mt][j] = -3.0e38f;
                    }
            }

            // online softmax: in-register reduce over 32 kpos + one shfl_xor(32)
            float mx = s[0][0];
            #pragma unroll
            for (int mt = 0; mt < 2; ++mt)
                #pragma unroll
                for (int j = 0; j < 16; ++j) mx = fmaxf(mx, s[mt][j]);
            mx = fmaxf(mx, __shfl_xor(mx, 32, 64));
            float mnew = fmaxf(m_i, mx);
            float alpha = __expf(m_i - mnew);
            float rs = 0.f;
            #pragma unroll
            for (int mt = 0; mt < 2; ++mt)
                #pragma unroll
                for (int j = 0; j < 16; ++j) {
                    float p = __expf(s[mt][j] - mnew);
                    s[mt][j] = p;
                    rs += p;
                }
            rs += __shfl_xor(rs, 32, 64);
            l_i = l_i * alpha + rs;
            m_i = mnew;
            #pragma unroll
            for (int em = 0; em < 4; ++em)
                #pragma unroll
                for (int j = 0; j < 16; ++j) acc[em][j] *= alpha;

            // P^T -> LDS: row q=l31 fixed, kpos cols contiguous per reg-group -> b64 writes
            #pragma unroll
            for (int mt = 0; mt < 2; ++mt)
                #pragma unroll
                for (int g = 0; g < 4; ++g) {
                    bf16x4 pk;
                    #pragma unroll
                    for (int i = 0; i < 4; ++i) pk[i] = (bf16_t)s[mt][g * 4 + i];
                    *(bf16x4*)&sP[wave][l31][mt * 32 + g * 8 + half * 4] = pk;
                }
            asm volatile("s_waitcnt lgkmcnt(0)" ::: "memory"); // per-wave sP: no barrier needed

            // ctx^T += V^T @ P  (4 e-mtiles x 4 kpos-ktiles)
            #pragma unroll
            for (int kc = 0; kc < 4; ++kc) {
                bf16x8 pf = *(const bf16x8*)&sP[wave][l31][kc * 16 + half * 8];
                #pragma unroll
                for (int em = 0; em < 4; ++em) {
                    bf16x8 vf = *(const bf16x8*)&sV[em * 32 + l31][kc * 16 + half * 8];
                    acc[em] = MFMA32(vf, pf, acc[em]);
                }
            }
            __syncthreads();
        }

        // epilogue: ctx^T col=q=l31 -> per-lane row of Ctx; e contiguous in reg groups
        const float inv = 1.f / l_i;
        bf16_t* Cp = Ctx + (size_t)(b * L_ + qrow) * 2048 + h * 128;
        #pragma unroll
        for (int em = 0; em < 4; ++em)
            #pragma unroll
            for (int g = 0; g < 4; ++g) {
                bf16x4 ov;
                #pragma unroll
                for (int i = 0; i < 4; ++i) ov[i] = (bf16_t)(acc[em][g * 4 + i] * inv);
                *(bf16x4*)&Cp[em * 32 + g * 8 + half * 4] = ov;
            }
    }
}

// ------------------------------------------ GELU(erf) + residual + LayerNorm, one row/block
__global__ __launch_bounds__(256) void ln_kernel(const float* __restrict__ Y,
                                                 const float* __restrict__ X,
                                                 const float* __restrict__ gamma,
                                                 const float* __restrict__ beta,
                                                 float* __restrict__ out) {
    __shared__ float sr[2048];
    __shared__ float wred[8];
    size_t row = blockIdx.x;
    const float* y = Y + row * 2048;
    const float* x = X + row * 2048;
    float sum = 0.f, ssq = 0.f;
    #pragma unroll
    for (int c = 0; c < 2; ++c) {
        int i = (c * 256 + threadIdx.x) * 4;
        float4 yv = *(const float4*)(y + i);
        float4 xv = *(const float4*)(x + i);
        float r0 = xv.x + 0.5f * yv.x * (1.f + erff(yv.x * 0.70710678118654752f));
        float r1 = xv.y + 0.5f * yv.y * (1.f + erff(yv.y * 0.70710678118654752f));
        float r2 = xv.z + 0.5f * yv.z * (1.f + erff(yv.z * 0.70710678118654752f));
        float r3 = xv.w + 0.5f * yv.w * (1.f + erff(yv.w * 0.70710678118654752f));
        sr[i] = r0; sr[i + 1] = r1; sr[i + 2] = r2; sr[i + 3] = r3;
        sum += r0 + r1 + r2 + r3;
        ssq += r0 * r0 + r1 * r1 + r2 * r2 + r3 * r3;
    }
    #pragma unroll
    for (int off = 32; off > 0; off >>= 1) {
        sum += __shfl_xor(sum, off, 64);
        ssq += __shfl_xor(ssq, off, 64);
    }
    int wv = threadIdx.x >> 6;
    if ((threadIdx.x & 63) == 0) { wred[wv] = sum; wred[wv + 4] = ssq; }
    __syncthreads();
    sum = wred[0] + wred[1] + wred[2] + wred[3];
    ssq = wred[4] + wred[5] + wred[6] + wred[7];
    float mu = sum * (1.f / 2048.f);
    float var = ssq * (1.f / 2048.f) - mu * mu;
    float rstd = rsqrtf(var + 1e-5f);
    #pragma unroll
    for (int c = 0; c < 2; ++c) {
        int i = (c * 256 + threadIdx.x) * 4;
        float4 gv = *(const float4*)(gamma + i);
        float4 bv = *(const float4*)(beta + i);
        float4 o;
        o.x = (sr[i]     - mu) * rstd * gv.x + bv.x;
        o.y = (sr[i + 1] - mu) * rstd * gv.y + bv.y;
        o.z = (sr[i + 2] - mu) * rstd * gv.z + bv.z;
        o.w = (sr[i + 3] - mu) * rstd * gv.w + bv.w;
        *(float4*)(out + row * 2048 + i) = o;
    }
}

// ----------------------------------------------------------------------------- launch
extern "C" void kernel_launch(void* const* d_in, const int* in_sizes, int n_in,
                              void* d_out, int out_size, void* d_ws, size_t ws_size,
                              hipStream_t stream) {
    const float* x     = (const float*)d_in[0];
    const float* Wq    = (const float*)d_in[1];
    const float* bq    = (const float*)d_in[2];
    const float* Wk    = (const float*)d_in[3];
    const float* bk    = (const float*)d_in[4];
    const float* Wv    = (const float*)d_in[5];
    const float* bv    = (const float*)d_in[6];
    const float* Wo    = (const float*)d_in[7];
    const float* bo    = (const float*)d_in[8];
    const float* gamma = (const float*)d_in[9];
    const float* beta  = (const float*)d_in[10];
    float* out = (float*)d_out;

    char* ws = (char*)d_ws;
    size_t off = 0;
    bf16_t* xb    = (bf16_t*)(ws + off); off += 16777216;   // 4096x2048 bf16
    bf16_t* WqkvT = (bf16_t*)(ws + off); off += 12582912;   // 3072x2048 bf16
    bf16_t* WoT   = (bf16_t*)(ws + off); off += 8388608;    // 2048x2048 bf16
    float*  qbias = (float*)(ws + off);  off += 12288;      // 3072 f32
    bf16_t* QKV   = (bf16_t*)(ws + off); off += 25165824;   // 4096x3072 bf16
    bf16_t* Vt    = (bf16_t*)(ws + off); off += 4194304;    // 8x128x2048 bf16
    bf16_t* Cb    = (bf16_t*)(ws + off); off += 16777216;   // 4096x2048 bf16
    float*  Yb    = (float*)(ws + off);  off += 33554432;   // 4096x2048 f32

    cast_bf16_kernel<<<8192, 256, 0, stream>>>(x, xb, M_ * D_);
    transpose_cast_kernel<<<dim3(64, 64), dim3(32, 8), 0, stream>>>(Wq, WqkvT, 2048, 2048);
    transpose_cast_kernel<<<dim3(16, 64), dim3(32, 8), 0, stream>>>(Wk, WqkvT + 2048 * 2048, 2048, 512);
    transpose_cast_kernel<<<dim3(16, 64), dim3(32, 8), 0, stream>>>(Wv, WqkvT + 2560 * 2048, 2048, 512);
    transpose_cast_kernel<<<dim3(64, 64), dim3(32, 8), 0, stream>>>(Wo, WoT, 2048, 2048);
    concat_bias_kernel<<<12, 256, 0, stream>>>(bq, bk, bv, qbias);

    gemm_kernel<true><<<dim3(24, 32), 256, 0, stream>>>(xb, WqkvT, qbias, QKV, M_, NQKV_, D_);
    transpose_v_kernel<<<dim3(4, 64, 8), dim3(32, 8), 0, stream>>>(QKV, Vt);
    attn_kernel<<<512, 128, 0, stream>>>(QKV, Vt, Cb);
    gemm_kernel<false><<<dim3(16, 32), 256, 0, stream>>>(Cb, WoT, bo, Yb, M_, D_, 2048);
    ln_kernel<<<M_, 256, 0, stream>>>(Yb, x, gamma, beta, out);
}

// Round 3
// 450.846 us; speedup vs baseline: 1.2798x; 1.1235x over previous
//
#include <hip/hip_runtime.h>
#include <hip/hip_bf16.h>
#include <math.h>

typedef __bf16 bf16_t;
typedef __bf16 bf16x4 __attribute__((ext_vector_type(4)));
typedef __bf16 bf16x8 __attribute__((ext_vector_type(8)));
typedef float  f32x4  __attribute__((ext_vector_type(4)));
typedef float  f32x16 __attribute__((ext_vector_type(16)));

#define MFMA16(a,b,c) __builtin_amdgcn_mfma_f32_16x16x32_bf16((a),(b),(c),0,0,0)
#define MFMA32(a,b,c) __builtin_amdgcn_mfma_f32_32x32x16_bf16((a),(b),(c),0,0,0)

// Problem constants
#define B_ 2
#define L_ 2048
#define D_ 2048
#define H_ 16
#define KV_ 4
#define E_ 128
#define M_ (B_*L_)      // 4096 rows
#define NQKV_ 3072      // H*E + 2*KV*E

// async global->LDS 16B (m97 pattern; LDS side is wave-uniform base + lane*16,
// so pass an LDS pointer that is linear in lane)
__device__ __forceinline__ void async_ld16(const bf16_t* g, bf16_t* l) {
    __builtin_amdgcn_global_load_lds((const __attribute__((address_space(1))) void*)g,
                                     (__attribute__((address_space(3))) void*)l, 16, 0, 0);
}

// ---------------------------------------------------------------- cast x -> bf16
__global__ __launch_bounds__(256) void cast_bf16_kernel(const float* __restrict__ src,
                                                        bf16_t* __restrict__ dst, int n) {
    int i = (blockIdx.x * 256 + threadIdx.x) * 4;
    if (i < n) {
        float4 v = *(const float4*)(src + i);
        bf16x4 o;
        o.x = (bf16_t)v.x; o.y = (bf16_t)v.y; o.z = (bf16_t)v.z; o.w = (bf16_t)v.w;
        *(bf16x4*)(dst + i) = o;
    }
}

// -------------------------------------------- transpose + cast: W[K,N] f32 -> WT[N,K] bf16
__global__ __launch_bounds__(256) void transpose_cast_kernel(const float* __restrict__ W,
                                                             bf16_t* __restrict__ WT,
                                                             int K, int N) {
    __shared__ float tile[32][33];
    int n0 = blockIdx.x * 32, k0 = blockIdx.y * 32;
    int tx = threadIdx.x, ty = threadIdx.y;  // 32 x 8
    #pragma unroll
    for (int i = 0; i < 32; i += 8)
        tile[ty + i][tx] = W[(size_t)(k0 + ty + i) * N + n0 + tx];
    __syncthreads();
    #pragma unroll
    for (int i = 0; i < 32; i += 8)
        WT[(size_t)(n0 + ty + i) * K + k0 + tx] = (bf16_t)tile[tx][ty + i];
}

// ---------------------------------------------------------------- concat qkv bias
__global__ void concat_bias_kernel(const float* __restrict__ bq, const float* __restrict__ bk,
                                   const float* __restrict__ bv, float* __restrict__ out) {
    int i = blockIdx.x * 256 + threadIdx.x;
    if (i < 2048) out[i] = bq[i];
    else if (i < 2560) out[i] = bk[i - 2048];
    else if (i < 3072) out[i] = bv[i - 2560];
}

// -------------------------------- V transpose: QKV[b,l,2560+kv*128+e] -> Vt[(b*4+kv)*128+e][l]
__global__ __launch_bounds__(256) void transpose_v_kernel(const bf16_t* __restrict__ QKV,
                                                          bf16_t* __restrict__ Vt) {
    __shared__ bf16_t tile[32][33];
    int e0 = blockIdx.x * 32, l0 = blockIdx.y * 32;
    int bk = blockIdx.z;                    // b*4 + kv
    int b = bk >> 2, kv = bk & 3;
    int tx = threadIdx.x, ty = threadIdx.y; // 32 x 8
    #pragma unroll
    for (int i = 0; i < 32; i += 8)
        tile[ty + i][tx] = QKV[(size_t)(b * L_ + l0 + ty + i) * NQKV_ + 2560 + kv * 128 + e0 + tx];
    __syncthreads();
    #pragma unroll
    for (int i = 0; i < 32; i += 8)
        Vt[((size_t)bk * 128 + e0 + ty + i) * L_ + l0 + tx] = tile[tx][ty + i];
}

// ---------------------------------------------------------------- bf16 MFMA GEMM
// C[M,N] = A[M,K] @ BT[N,K]^T + bias ; 128x128 tile, 4 waves, 4x4 16x16x32 MFMAs/wave
// staging via global_load_lds width 16 (m97)
template <bool OUT_BF16>
__global__ __launch_bounds__(256) void gemm_kernel(const bf16_t* __restrict__ A,
                                                   const bf16_t* __restrict__ BT,
                                                   const float* __restrict__ bias,
                                                   void* __restrict__ C,
                                                   int M, int N, int K) {
    __shared__ __align__(16) bf16_t sA[128][32];
    __shared__ __align__(16) bf16_t sB[128][32];
    int tid = threadIdx.x;
    int wave = tid >> 6, lane = tid & 63;
    int l16 = lane & 15, quad = lane >> 4;
    int row0 = blockIdx.y * 128;
    int col0 = blockIdx.x * 128;
    int wm = (wave >> 1) * 64;
    int wn = (wave & 1) * 64;

    f32x4 acc[4][4];
    #pragma unroll
    for (int i = 0; i < 4; ++i)
        #pragma unroll
        for (int j = 0; j < 4; ++j)
            acc[i][j] = f32x4{0.f, 0.f, 0.f, 0.f};

    for (int k0 = 0; k0 < K; k0 += 32) {
        #pragma unroll
        for (int c = 0; c < 2; ++c) {
            int lin = (c * 256 + tid) * 8;
            int r = lin >> 5, col = lin & 31;
            async_ld16(&A[(size_t)(row0 + r) * K + k0 + col], &sA[r][col]);
            async_ld16(&BT[(size_t)(col0 + r) * K + k0 + col], &sB[r][col]);
        }
        __syncthreads();
        bf16x8 af[4], bf[4];
        #pragma unroll
        for (int mt = 0; mt < 4; ++mt) af[mt] = *(const bf16x8*)&sA[wm + mt * 16 + l16][quad * 8];
        #pragma unroll
        for (int nt = 0; nt < 4; ++nt) bf[nt] = *(const bf16x8*)&sB[wn + nt * 16 + l16][quad * 8];
        #pragma unroll
        for (int mt = 0; mt < 4; ++mt)
            #pragma unroll
            for (int nt = 0; nt < 4; ++nt)
                acc[mt][nt] = MFMA16(af[mt], bf[nt], acc[mt][nt]);
        __syncthreads();
    }

    #pragma unroll
    for (int mt = 0; mt < 4; ++mt) {
        #pragma unroll
        for (int nt = 0; nt < 4; ++nt) {
            int gcol = col0 + wn + nt * 16 + l16;
            float bv = bias[gcol];
            #pragma unroll
            for (int r = 0; r < 4; ++r) {
                int grow = row0 + wm + mt * 16 + quad * 4 + r;
                float v = acc[mt][nt][r] + bv;
                if (OUT_BF16) ((bf16_t*)C)[(size_t)grow * N + gcol] = (bf16_t)v;
                else          ((float*)C)[(size_t)grow * N + gcol] = v;
            }
        }
    }
}

// ---------------------------------------------------------------- flash attention (causal GQA)
// S^T = K@Q^T, ctx^T = V^T@P. One 64-row q-tile per block (2 waves, 32 q/wave);
// grid 1024 = B*H*32, qt reversed so heavy tiles dispatch first.
// LDS = exactly 40960 B -> 4 blocks/CU; unpadded + 16B-chunk XOR swizzle;
// K/V staged via global_load_lds (swizzle applied on the global address).
__global__ __launch_bounds__(128) void attn_kernel(const bf16_t* __restrict__ QKV,
                                                   const bf16_t* __restrict__ Vt,
                                                   bf16_t* __restrict__ Ctx) {
    __shared__ __align__(16) bf16_t sK[64][128];    // [kpos][e], chunk ^= kpos&15
    __shared__ __align__(16) bf16_t sV[128][64];    // [e][kpos], chunk ^= e&7
    __shared__ __align__(16) bf16_t sP[2][32][64];  // per-wave P^T [q][kpos], chunk ^= q&7

    const int tid = threadIdx.x;
    const int wave = tid >> 6, lane = tid & 63;
    const int l31 = lane & 31, half = lane >> 5;
    const int qt = 31 - (blockIdx.x & 31);
    const int h = (blockIdx.x >> 5) & 15;
    const int b = blockIdx.x >> 9;
    const int kv = h & 3;

    const bf16_t* Kbase = QKV + (size_t)b * L_ * NQKV_ + 2048 + kv * 128;
    const bf16_t* Vbase = Vt + (size_t)(b * 4 + kv) * 128 * L_;
    const float scale = 0.08838834764831845f; // 1/sqrt(128)

    const int q0 = qt * 64;
    const int qrow = q0 + wave * 32 + l31;   // this lane's q row (stats + B-frag n)

    // Q fragments (B-operand: n=q=l31, k=e)
    bf16x8 qf[8];
    const bf16_t* Qrow = QKV + (size_t)(b * L_ + qrow) * NQKV_ + h * 128 + half * 8;
    #pragma unroll
    for (int et = 0; et < 8; ++et) qf[et] = *(const bf16x8*)&Qrow[et * 16];

    f32x16 acc[4];
    #pragma unroll
    for (int em = 0; em < 4; ++em)
        #pragma unroll
        for (int j = 0; j < 16; ++j) acc[em][j] = 0.f;
    float m_i = -3.0e38f, l_i = 0.f;

    for (int kt = 0; kt <= qt; ++kt) {
        const int kk0 = kt * 64;
        // async stage K[64x128] (1024 chunks) and V^T[128x64] (1024 chunks); wave w
        // covers chunks [w*512, w*512+512). Swizzle rides on the global address.
        bf16_t* sKf = &sK[0][0];
        bf16_t* sVf = &sV[0][0];
        #pragma unroll
        for (int p = 0; p < 8; ++p) {
            int ch = wave * 512 + p * 64 + lane;
            int rk = ch >> 4, ck = ch & 15;
            async_ld16(Kbase + (size_t)(kk0 + rk) * NQKV_ + ((ck ^ (rk & 15)) << 3), sKf + ch * 8);
            int rv = ch >> 3, cv = ch & 7;
            async_ld16(Vbase + (size_t)rv * L_ + kk0 + ((cv ^ (rv & 7)) << 3), sVf + ch * 8);
        }
        __syncthreads();

        // S^T[kpos][q] = K @ Q^T  (2 kpos-mtiles x 8 e-ktiles)
        f32x16 s[2];
        #pragma unroll
        for (int mt = 0; mt < 2; ++mt)
            #pragma unroll
            for (int j = 0; j < 16; ++j) s[mt][j] = 0.f;
        #pragma unroll
        for (int mt = 0; mt < 2; ++mt)
            #pragma unroll
            for (int et = 0; et < 8; ++et) {
                int ck = (et * 2 + half) ^ (l31 & 15);
                bf16x8 kf = *(const bf16x8*)&sK[mt * 32 + l31][ck * 8];
                s[mt] = MFMA32(kf, qf[et], s[mt]);
            }

        #pragma unroll
        for (int mt = 0; mt < 2; ++mt)
            #pragma unroll
            for (int j = 0; j < 16; ++j) s[mt][j] *= scale;

        // causal mask: only the diagonal tile needs it (kpos row = (j&3)+8*(j>>2)+4*half)
        if (kt == qt) {
            #pragma unroll
            for (int mt = 0; mt < 2; ++mt)
                #pragma unroll
                for (int j = 0; j < 16; ++j) {
                    int kidx = kk0 + mt * 32 + (j & 3) + 8 * (j >> 2) + 4 * half;
                    if (kidx > qrow) s[mt][j] = -3.0e38f;
                }
        }

        // online softmax: in-register reduce over 32 kpos + one shfl_xor(32)
        float mx = s[0][0];
        #pragma unroll
        for (int mt = 0; mt < 2; ++mt)
            #pragma unroll
            for (int j = 0; j < 16; ++j) mx = fmaxf(mx, s[mt][j]);
        mx = fmaxf(mx, __shfl_xor(mx, 32, 64));
        float mnew = fmaxf(m_i, mx);
        float alpha = __expf(m_i - mnew);
        float rs = 0.f;
        #pragma unroll
        for (int mt = 0; mt < 2; ++mt)
            #pragma unroll
            for (int j = 0; j < 16; ++j) {
                float p = __expf(s[mt][j] - mnew);
                s[mt][j] = p;
                rs += p;
            }
        rs += __shfl_xor(rs, 32, 64);
        l_i = l_i * alpha + rs;
        m_i = mnew;
        #pragma unroll
        for (int em = 0; em < 4; ++em)
            #pragma unroll
            for (int j = 0; j < 16; ++j) acc[em][j] *= alpha;

        // P^T -> LDS (per-wave, swizzled): row q=l31, b64 writes per (mt,g) group
        #pragma unroll
        for (int mt = 0; mt < 2; ++mt)
            #pragma unroll
            for (int g = 0; g < 4; ++g) {
                bf16x4 pk;
                #pragma unroll
                for (int i = 0; i < 4; ++i) pk[i] = (bf16_t)s[mt][g * 4 + i];
                int chp = (mt * 4 + g) ^ (l31 & 7);
                *(bf16x4*)&sP[wave][l31][chp * 8 + half * 4] = pk;
            }
        asm volatile("s_waitcnt lgkmcnt(0)" ::: "memory"); // per-wave sP: no barrier needed

        // ctx^T += V^T @ P  (4 e-mtiles x 4 kpos-ktiles)
        #pragma unroll
        for (int kc = 0; kc < 4; ++kc) {
            int cp = (kc * 2 + half) ^ (l31 & 7);
            bf16x8 pf = *(const bf16x8*)&sP[wave][l31][cp * 8];
            #pragma unroll
            for (int em = 0; em < 4; ++em) {
                int cvv = (kc * 2 + half) ^ (l31 & 7);
                bf16x8 vf = *(const bf16x8*)&sV[em * 32 + l31][cvv * 8];
                acc[em] = MFMA32(vf, pf, acc[em]);
            }
        }
        __syncthreads();
    }

    // epilogue: ctx^T col=q=l31 -> per-lane row of Ctx; e contiguous in reg groups
    const float inv = 1.f / l_i;
    bf16_t* Cp = Ctx + (size_t)(b * L_ + qrow) * 2048 + h * 128;
    #pragma unroll
    for (int em = 0; em < 4; ++em)
        #pragma unroll
        for (int g = 0; g < 4; ++g) {
            bf16x4 ov;
            #pragma unroll
            for (int i = 0; i < 4; ++i) ov[i] = (bf16_t)(acc[em][g * 4 + i] * inv);
            *(bf16x4*)&Cp[em * 32 + g * 8 + half * 4] = ov;
        }
}

// ------------------------------------------ GELU(erf) + residual + LayerNorm, one row/block
__global__ __launch_bounds__(256) void ln_kernel(const float* __restrict__ Y,
                                                 const float* __restrict__ X,
                                                 const float* __restrict__ gamma,
                                                 const float* __restrict__ beta,
                                                 float* __restrict__ out) {
    __shared__ float sr[2048];
    __shared__ float wred[8];
    size_t row = blockIdx.x;
    const float* y = Y + row * 2048;
    const float* x = X + row * 2048;
    float sum = 0.f, ssq = 0.f;
    #pragma unroll
    for (int c = 0; c < 2; ++c) {
        int i = (c * 256 + threadIdx.x) * 4;
        float4 yv = *(const float4*)(y + i);
        float4 xv = *(const float4*)(x + i);
        float r0 = xv.x + 0.5f * yv.x * (1.f + erff(yv.x * 0.70710678118654752f));
        float r1 = xv.y + 0.5f * yv.y * (1.f + erff(yv.y * 0.70710678118654752f));
        float r2 = xv.z + 0.5f * yv.z * (1.f + erff(yv.z * 0.70710678118654752f));
        float r3 = xv.w + 0.5f * yv.w * (1.f + erff(yv.w * 0.70710678118654752f));
        sr[i] = r0; sr[i + 1] = r1; sr[i + 2] = r2; sr[i + 3] = r3;
        sum += r0 + r1 + r2 + r3;
        ssq += r0 * r0 + r1 * r1 + r2 * r2 + r3 * r3;
    }
    #pragma unroll
    for (int off = 32; off > 0; off >>= 1) {
        sum += __shfl_xor(sum, off, 64);
        ssq += __shfl_xor(ssq, off, 64);
    }
    int wv = threadIdx.x >> 6;
    if ((threadIdx.x & 63) == 0) { wred[wv] = sum; wred[wv + 4] = ssq; }
    __syncthreads();
    sum = wred[0] + wred[1] + wred[2] + wred[3];
    ssq = wred[4] + wred[5] + wred[6] + wred[7];
    float mu = sum * (1.f / 2048.f);
    float var = ssq * (1.f / 2048.f) - mu * mu;
    float rstd = rsqrtf(var + 1e-5f);
    #pragma unroll
    for (int c = 0; c < 2; ++c) {
        int i = (c * 256 + threadIdx.x) * 4;
        float4 gv = *(const float4*)(gamma + i);
        float4 bv = *(const float4*)(beta + i);
        float4 o;
        o.x = (sr[i]     - mu) * rstd * gv.x + bv.x;
        o.y = (sr[i + 1] - mu) * rstd * gv.y + bv.y;
        o.z = (sr[i + 2] - mu) * rstd * gv.z + bv.z;
        o.w = (sr[i + 3] - mu) * rstd * gv.w + bv.w;
        *(float4*)(out + row * 2048 + i) = o;
    }
}

// ----------------------------------------------------------------------------- launch
extern "C" void kernel_launch(void* const* d_in, const int* in_sizes, int n_in,
                              void* d_out, int out_size, void* d_ws, size_t ws_size,
                              hipStream_t stream) {
    const float* x     = (const float*)d_in[0];
    const float* Wq    = (const float*)d_in[1];
    const float* bq    = (const float*)d_in[2];
    const float* Wk    = (const float*)d_in[3];
    const float* bk    = (const float*)d_in[4];
    const float* Wv    = (const float*)d_in[5];
    const float* bv    = (const float*)d_in[6];
    const float* Wo    = (const float*)d_in[7];
    const float* bo    = (const float*)d_in[8];
    const float* gamma = (const float*)d_in[9];
    const float* beta  = (const float*)d_in[10];
    float* out = (float*)d_out;

    char* ws = (char*)d_ws;
    size_t off = 0;
    bf16_t* xb    = (bf16_t*)(ws + off); off += 16777216;   // 4096x2048 bf16
    bf16_t* WqkvT = (bf16_t*)(ws + off); off += 12582912;   // 3072x2048 bf16
    bf16_t* WoT   = (bf16_t*)(ws + off); off += 8388608;    // 2048x2048 bf16
    float*  qbias = (float*)(ws + off);  off += 12288;      // 3072 f32
    bf16_t* QKV   = (bf16_t*)(ws + off); off += 25165824;   // 4096x3072 bf16
    bf16_t* Vt    = (bf16_t*)(ws + off); off += 4194304;    // 8x128x2048 bf16
    bf16_t* Cb    = (bf16_t*)(ws + off); off += 16777216;   // 4096x2048 bf16
    float*  Yb    = (float*)(ws + off);  off += 33554432;   // 4096x2048 f32

    cast_bf16_kernel<<<8192, 256, 0, stream>>>(x, xb, M_ * D_);
    transpose_cast_kernel<<<dim3(64, 64), dim3(32, 8), 0, stream>>>(Wq, WqkvT, 2048, 2048);
    transpose_cast_kernel<<<dim3(16, 64), dim3(32, 8), 0, stream>>>(Wk, WqkvT + 2048 * 2048, 2048, 512);
    transpose_cast_kernel<<<dim3(16, 64), dim3(32, 8), 0, stream>>>(Wv, WqkvT + 2560 * 2048, 2048, 512);
    transpose_cast_kernel<<<dim3(64, 64), dim3(32, 8), 0, stream>>>(Wo, WoT, 2048, 2048);
    concat_bias_kernel<<<12, 256, 0, stream>>>(bq, bk, bv, qbias);

    gemm_kernel<true><<<dim3(24, 32), 256, 0, stream>>>(xb, WqkvT, qbias, QKV, M_, NQKV_, D_);
    transpose_v_kernel<<<dim3(4, 64, 8), dim3(32, 8), 0, stream>>>(QKV, Vt);
    attn_kernel<<<1024, 128, 0, stream>>>(QKV, Vt, Cb);
    gemm_kernel<false><<<dim3(16, 32), 256, 0, stream>>>(Cb, WoT, bo, Yb, M_, D_, 2048);
    ln_kernel<<<M_, 256, 0, stream>>>(Yb, x, gamma, beta, out);
}

// Round 4
// 423.614 us; speedup vs baseline: 1.3621x; 1.0643x over previous
//
#include <hip/hip_runtime.h>
#include <hip/hip_bf16.h>
#include <math.h>

typedef __bf16 bf16_t;
typedef __bf16 bf16x4 __attribute__((ext_vector_type(4)));
typedef __bf16 bf16x8 __attribute__((ext_vector_type(8)));
typedef float  f32x4  __attribute__((ext_vector_type(4)));
typedef float  f32x16 __attribute__((ext_vector_type(16)));

#define MFMA16(a,b,c) __builtin_amdgcn_mfma_f32_16x16x32_bf16((a),(b),(c),0,0,0)
#define MFMA32(a,b,c) __builtin_amdgcn_mfma_f32_32x32x16_bf16((a),(b),(c),0,0,0)

// Problem constants
#define B_ 2
#define L_ 2048
#define D_ 2048
#define H_ 16
#define KV_ 4
#define E_ 128
#define M_ (B_*L_)      // 4096 rows
#define NQKV_ 3072      // H*E + 2*KV*E

// async global->LDS 16B (m97 pattern; LDS dest is wave-uniform base + lane*16)
__device__ __forceinline__ void async_ld16(const bf16_t* g, bf16_t* l) {
    __builtin_amdgcn_global_load_lds((const __attribute__((address_space(1))) void*)g,
                                     (__attribute__((address_space(3))) void*)l, 16, 0, 0);
}

// ---------------------------------------------------------------- cast x -> bf16
__global__ __launch_bounds__(256) void cast_bf16_kernel(const float* __restrict__ src,
                                                        bf16_t* __restrict__ dst, int n) {
    int i = (blockIdx.x * 256 + threadIdx.x) * 4;
    if (i < n) {
        float4 v = *(const float4*)(src + i);
        bf16x4 o;
        o.x = (bf16_t)v.x; o.y = (bf16_t)v.y; o.z = (bf16_t)v.z; o.w = (bf16_t)v.w;
        *(bf16x4*)(dst + i) = o;
    }
}

// -------------------------------------------- transpose + cast: W[K,N] f32 -> WT[N,K] bf16
__global__ __launch_bounds__(256) void transpose_cast_kernel(const float* __restrict__ W,
                                                             bf16_t* __restrict__ WT,
                                                             int K, int N) {
    __shared__ float tile[32][33];
    int n0 = blockIdx.x * 32, k0 = blockIdx.y * 32;
    int tx = threadIdx.x, ty = threadIdx.y;  // 32 x 8
    #pragma unroll
    for (int i = 0; i < 32; i += 8)
        tile[ty + i][tx] = W[(size_t)(k0 + ty + i) * N + n0 + tx];
    __syncthreads();
    #pragma unroll
    for (int i = 0; i < 32; i += 8)
        WT[(size_t)(n0 + ty + i) * K + k0 + tx] = (bf16_t)tile[tx][ty + i];
}

// ---------------------------------------------------------------- concat qkv bias
__global__ void concat_bias_kernel(const float* __restrict__ bq, const float* __restrict__ bk,
                                   const float* __restrict__ bv, float* __restrict__ out) {
    int i = blockIdx.x * 256 + threadIdx.x;
    if (i < 2048) out[i] = bq[i];
    else if (i < 2560) out[i] = bk[i - 2048];
    else if (i < 3072) out[i] = bv[i - 2560];
}

// -------------------------------- V transpose: QKV[b,l,2560+kv*128+e] -> Vt[(b*4+kv)*128+e][l]
__global__ __launch_bounds__(256) void transpose_v_kernel(const bf16_t* __restrict__ QKV,
                                                          bf16_t* __restrict__ Vt) {
    __shared__ bf16_t tile[32][33];
    int e0 = blockIdx.x * 32, l0 = blockIdx.y * 32;
    int bk = blockIdx.z;                    // b*4 + kv
    int b = bk >> 2, kv = bk & 3;
    int tx = threadIdx.x, ty = threadIdx.y; // 32 x 8
    #pragma unroll
    for (int i = 0; i < 32; i += 8)
        tile[ty + i][tx] = QKV[(size_t)(b * L_ + l0 + ty + i) * NQKV_ + 2560 + kv * 128 + e0 + tx];
    __syncthreads();
    #pragma unroll
    for (int i = 0; i < 32; i += 8)
        Vt[((size_t)bk * 128 + e0 + ty + i) * L_ + l0 + tx] = tile[tx][ty + i];
}

// ---------------------------------------------------------------- bf16 MFMA GEMM
// C[M,N] = A[M,K] @ BT[N,K]^T + bias ; 128x128 tile, 4 waves, 4x4 16x16x32 MFMAs/wave
// staging via global_load_lds width 16 (m97)
template <bool OUT_BF16>
__global__ __launch_bounds__(256) void gemm_kernel(const bf16_t* __restrict__ A,
                                                   const bf16_t* __restrict__ BT,
                                                   const float* __restrict__ bias,
                                                   void* __restrict__ C,
                                                   int M, int N, int K) {
    __shared__ __align__(16) bf16_t sA[128][32];
    __shared__ __align__(16) bf16_t sB[128][32];
    int tid = threadIdx.x;
    int wave = tid >> 6, lane = tid & 63;
    int l16 = lane & 15, quad = lane >> 4;
    int row0 = blockIdx.y * 128;
    int col0 = blockIdx.x * 128;
    int wm = (wave >> 1) * 64;
    int wn = (wave & 1) * 64;

    f32x4 acc[4][4];
    #pragma unroll
    for (int i = 0; i < 4; ++i)
        #pragma unroll
        for (int j = 0; j < 4; ++j)
            acc[i][j] = f32x4{0.f, 0.f, 0.f, 0.f};

    for (int k0 = 0; k0 < K; k0 += 32) {
        #pragma unroll
        for (int c = 0; c < 2; ++c) {
            int lin = (c * 256 + tid) * 8;
            int r = lin >> 5, col = lin & 31;
            async_ld16(&A[(size_t)(row0 + r) * K + k0 + col], &sA[r][col]);
            async_ld16(&BT[(size_t)(col0 + r) * K + k0 + col], &sB[r][col]);
        }
        __syncthreads();
        bf16x8 af[4], bf[4];
        #pragma unroll
        for (int mt = 0; mt < 4; ++mt) af[mt] = *(const bf16x8*)&sA[wm + mt * 16 + l16][quad * 8];
        #pragma unroll
        for (int nt = 0; nt < 4; ++nt) bf[nt] = *(const bf16x8*)&sB[wn + nt * 16 + l16][quad * 8];
        #pragma unroll
        for (int mt = 0; mt < 4; ++mt)
            #pragma unroll
            for (int nt = 0; nt < 4; ++nt)
                acc[mt][nt] = MFMA16(af[mt], bf[nt], acc[mt][nt]);
        __syncthreads();
    }

    #pragma unroll
    for (int mt = 0; mt < 4; ++mt) {
        #pragma unroll
        for (int nt = 0; nt < 4; ++nt) {
            int gcol = col0 + wn + nt * 16 + l16;
            float bv = bias[gcol];
            #pragma unroll
            for (int r = 0; r < 4; ++r) {
                int grow = row0 + wm + mt * 16 + quad * 4 + r;
                float v = acc[mt][nt][r] + bv;
                if (OUT_BF16) ((bf16_t*)C)[(size_t)grow * N + gcol] = (bf16_t)v;
                else          ((float*)C)[(size_t)grow * N + gcol] = v;
            }
        }
    }
}

// ---------------------------------------------------------------- flash attention (causal GQA)
// S^T = K@Q^T, ctx^T = V^T@P. Block = 256 threads = 2 units x 2 waves.
// Unit 0 computes q-tile `pair`, unit 1 computes q-tile `31-pair`; both share one
// padded sK/sV staging (same kv head). Block iterates kt=0..31-pair (17..32 iters,
// near-uniform); unit 0 guards compute by kt<=pair. Grid 512 x 4 waves = 8 waves/CU
// (LDS 54272 -> 2 blocks/CU, VGPR ~208 -> 2 waves/SIMD).
__global__ __launch_bounds__(256) void attn_kernel(const bf16_t* __restrict__ QKV,
                                                   const bf16_t* __restrict__ Vt,
                                                   bf16_t* __restrict__ Ctx) {
    __shared__ __align__(16) bf16_t sK[64][136];    // [kpos][e], +8 pad
    __shared__ __align__(16) bf16_t sV[128][72];    // [e][kpos], +8 pad
    __shared__ __align__(16) bf16_t sP[4][32][72];  // per-wave P^T [q][kpos], +8 pad

    const int tid = threadIdx.x;
    const int wave = tid >> 6, lane = tid & 63;
    const int unit = wave >> 1, wv = wave & 1;
    const int l31 = lane & 31, half = lane >> 5;
    const int pair = blockIdx.x & 15;
    const int h = (blockIdx.x >> 4) & 15;
    const int b = blockIdx.x >> 8;
    const int kv = h & 3;

    const bf16_t* Kbase = QKV + (size_t)b * L_ * NQKV_ + 2048 + kv * 128;
    const bf16_t* Vbase = Vt + (size_t)(b * 4 + kv) * 128 * L_;
    const float scale = 0.08838834764831845f; // 1/sqrt(128)

    const int t_u = unit ? 31 - pair : pair;   // this unit's q-tile
    const int ktmax = 31 - pair;               // block iterates 0..ktmax
    const int qrow = t_u * 64 + wv * 32 + l31; // this lane's q row

    // Q fragments (B-operand: n=q=l31, k=e)
    bf16x8 qf[8];
    const bf16_t* Qrow = QKV + (size_t)(b * L_ + qrow) * NQKV_ + h * 128 + half * 8;
    #pragma unroll
    for (int et = 0; et < 8; ++et) qf[et] = *(const bf16x8*)&Qrow[et * 16];

    f32x16 acc[4];
    #pragma unroll
    for (int em = 0; em < 4; ++em)
        #pragma unroll
        for (int j = 0; j < 16; ++j) acc[em][j] = 0.f;
    float m_i = -3.0e38f, l_i = 0.f;

    for (int kt = 0; kt <= ktmax; ++kt) {
        const int kk0 = kt * 64;
        // all 256 threads stage shared K[64x128] + V^T[128x64]: 4 chunks each
        #pragma unroll
        for (int p = 0; p < 4; ++p) {
            int ch = p * 256 + tid;
            int rk = ch >> 4, ck = ch & 15;
            *(bf16x8*)&sK[rk][ck * 8] = *(const bf16x8*)&Kbase[(size_t)(kk0 + rk) * NQKV_ + ck * 8];
            int rv = ch >> 3, cv = ch & 7;
            *(bf16x8*)&sV[rv][cv * 8] = *(const bf16x8*)&Vbase[(size_t)rv * L_ + kk0 + cv * 8];
        }
        __syncthreads();

        if (kt <= t_u) {
            // S^T[kpos][q] = K @ Q^T  (2 kpos-mtiles x 8 e-ktiles)
            f32x16 s[2];
            #pragma unroll
            for (int mt = 0; mt < 2; ++mt)
                #pragma unroll
                for (int j = 0; j < 16; ++j) s[mt][j] = 0.f;
            #pragma unroll
            for (int mt = 0; mt < 2; ++mt)
                #pragma unroll
                for (int et = 0; et < 8; ++et) {
                    bf16x8 kf = *(const bf16x8*)&sK[mt * 32 + l31][et * 16 + half * 8];
                    s[mt] = MFMA32(kf, qf[et], s[mt]);
                }

            #pragma unroll
            for (int mt = 0; mt < 2; ++mt)
                #pragma unroll
                for (int j = 0; j < 16; ++j) s[mt][j] *= scale;

            // causal mask on the diagonal tile (kpos row = (j&3)+8*(j>>2)+4*half)
            if (kt == t_u) {
                #pragma unroll
                for (int mt = 0; mt < 2; ++mt)
                    #pragma unroll
                    for (int j = 0; j < 16; ++j) {
                        int kidx = kk0 + mt * 32 + (j & 3) + 8 * (j >> 2) + 4 * half;
                        if (kidx > qrow) s[mt][j] = -3.0e38f;
                    }
            }

            // online softmax: in-register reduce over 32 kpos + one shfl_xor(32)
            float mx = s[0][0];
            #pragma unroll
            for (int mt = 0; mt < 2; ++mt)
                #pragma unroll
                for (int j = 0; j < 16; ++j) mx = fmaxf(mx, s[mt][j]);
            mx = fmaxf(mx, __shfl_xor(mx, 32, 64));
            float mnew = fmaxf(m_i, mx);
            float alpha = __expf(m_i - mnew);
            float rs = 0.f;
            #pragma unroll
            for (int mt = 0; mt < 2; ++mt)
                #pragma unroll
                for (int j = 0; j < 16; ++j) {
                    float p = __expf(s[mt][j] - mnew);
                    s[mt][j] = p;
                    rs += p;
                }
            rs += __shfl_xor(rs, 32, 64);
            l_i = l_i * alpha + rs;
            m_i = mnew;
            #pragma unroll
            for (int em = 0; em < 4; ++em)
                #pragma unroll
                for (int j = 0; j < 16; ++j) acc[em][j] *= alpha;

            // P^T -> per-wave LDS: row q=l31, b64 writes per (mt,g) group
            #pragma unroll
            for (int mt = 0; mt < 2; ++mt)
                #pragma unroll
                for (int g = 0; g < 4; ++g) {
                    bf16x4 pk;
                    #pragma unroll
                    for (int i = 0; i < 4; ++i) pk[i] = (bf16_t)s[mt][g * 4 + i];
                    *(bf16x4*)&sP[wave][l31][mt * 32 + g * 8 + half * 4] = pk;
                }
            asm volatile("s_waitcnt lgkmcnt(0)" ::: "memory"); // per-wave sP

            // ctx^T += V^T @ P  (4 e-mtiles x 4 kpos-ktiles)
            #pragma unroll
            for (int kc = 0; kc < 4; ++kc) {
                bf16x8 pf = *(const bf16x8*)&sP[wave][l31][kc * 16 + half * 8];
                #pragma unroll
                for (int em = 0; em < 4; ++em) {
                    bf16x8 vf = *(const bf16x8*)&sV[em * 32 + l31][kc * 16 + half * 8];
                    acc[em] = MFMA32(vf, pf, acc[em]);
                }
            }
        }
        __syncthreads();
    }

    // epilogue: ctx^T col=q=l31 -> per-lane row of Ctx; e contiguous in reg groups
    const float inv = 1.f / l_i;
    bf16_t* Cp = Ctx + (size_t)(b * L_ + qrow) * 2048 + h * 128;
    #pragma unroll
    for (int em = 0; em < 4; ++em)
        #pragma unroll
        for (int g = 0; g < 4; ++g) {
            bf16x4 ov;
            #pragma unroll
            for (int i = 0; i < 4; ++i) ov[i] = (bf16_t)(acc[em][g * 4 + i] * inv);
            *(bf16x4*)&Cp[em * 32 + g * 8 + half * 4] = ov;
        }
}

// ------------------------------------------ GELU(erf) + residual + LayerNorm, one row/block
__global__ __launch_bounds__(256) void ln_kernel(const float* __restrict__ Y,
                                                 const float* __restrict__ X,
                                                 const float* __restrict__ gamma,
                                                 const float* __restrict__ beta,
                                                 float* __restrict__ out) {
    __shared__ float sr[2048];
    __shared__ float wred[8];
    size_t row = blockIdx.x;
    const float* y = Y + row * 2048;
    const float* x = X + row * 2048;
    float sum = 0.f, ssq = 0.f;
    #pragma unroll
    for (int c = 0; c < 2; ++c) {
        int i = (c * 256 + threadIdx.x) * 4;
        float4 yv = *(const float4*)(y + i);
        float4 xv = *(const float4*)(x + i);
        float r0 = xv.x + 0.5f * yv.x * (1.f + erff(yv.x * 0.70710678118654752f));
        float r1 = xv.y + 0.5f * yv.y * (1.f + erff(yv.y * 0.70710678118654752f));
        float r2 = xv.z + 0.5f * yv.z * (1.f + erff(yv.z * 0.70710678118654752f));
        float r3 = xv.w + 0.5f * yv.w * (1.f + erff(yv.w * 0.70710678118654752f));
        sr[i] = r0; sr[i + 1] = r1; sr[i + 2] = r2; sr[i + 3] = r3;
        sum += r0 + r1 + r2 + r3;
        ssq += r0 * r0 + r1 * r1 + r2 * r2 + r3 * r3;
    }
    #pragma unroll
    for (int off = 32; off > 0; off >>= 1) {
        sum += __shfl_xor(sum, off, 64);
        ssq += __shfl_xor(ssq, off, 64);
    }
    int wv = threadIdx.x >> 6;
    if ((threadIdx.x & 63) == 0) { wred[wv] = sum; wred[wv + 4] = ssq; }
    __syncthreads();
    sum = wred[0] + wred[1] + wred[2] + wred[3];
    ssq = wred[4] + wred[5] + wred[6] + wred[7];
    float mu = sum * (1.f / 2048.f);
    float var = ssq * (1.f / 2048.f) - mu * mu;
    float rstd = rsqrtf(var + 1e-5f);
    #pragma unroll
    for (int c = 0; c < 2; ++c) {
        int i = (c * 256 + threadIdx.x) * 4;
        float4 gv = *(const float4*)(gamma + i);
        float4 bv = *(const float4*)(beta + i);
        float4 o;
        o.x = (sr[i]     - mu) * rstd * gv.x + bv.x;
        o.y = (sr[i + 1] - mu) * rstd * gv.y + bv.y;
        o.z = (sr[i + 2] - mu) * rstd * gv.z + bv.z;
        o.w = (sr[i + 3] - mu) * rstd * gv.w + bv.w;
        *(float4*)(out + row * 2048 + i) = o;
    }
}

// ----------------------------------------------------------------------------- launch
extern "C" void kernel_launch(void* const* d_in, const int* in_sizes, int n_in,
                              void* d_out, int out_size, void* d_ws, size_t ws_size,
                              hipStream_t stream) {
    const float* x     = (const float*)d_in[0];
    const float* Wq    = (const float*)d_in[1];
    const float* bq    = (const float*)d_in[2];
    const float* Wk    = (const float*)d_in[3];
    const float* bk    = (const float*)d_in[4];
    const float* Wv    = (const float*)d_in[5];
    const float* bv    = (const float*)d_in[6];
    const float* Wo    = (const float*)d_in[7];
    const float* bo    = (const float*)d_in[8];
    const float* gamma = (const float*)d_in[9];
    const float* beta  = (const float*)d_in[10];
    float* out = (float*)d_out;

    char* ws = (char*)d_ws;
    size_t off = 0;
    bf16_t* xb    = (bf16_t*)(ws + off); off += 16777216;   // 4096x2048 bf16
    bf16_t* WqkvT = (bf16_t*)(ws + off); off += 12582912;   // 3072x2048 bf16
    bf16_t* WoT   = (bf16_t*)(ws + off); off += 8388608;    // 2048x2048 bf16
    float*  qbias = (float*)(ws + off);  off += 12288;      // 3072 f32
    bf16_t* QKV   = (bf16_t*)(ws + off); off += 25165824;   // 4096x3072 bf16
    bf16_t* Vt    = (bf16_t*)(ws + off); off += 4194304;    // 8x128x2048 bf16
    bf16_t* Cb    = (bf16_t*)(ws + off); off += 16777216;   // 4096x2048 bf16
    float*  Yb    = (float*)(ws + off);  off += 33554432;   // 4096x2048 f32

    cast_bf16_kernel<<<8192, 256, 0, stream>>>(x, xb, M_ * D_);
    transpose_cast_kernel<<<dim3(64, 64), dim3(32, 8), 0, stream>>>(Wq, WqkvT, 2048, 2048);
    transpose_cast_kernel<<<dim3(16, 64), dim3(32, 8), 0, stream>>>(Wk, WqkvT + 2048 * 2048, 2048, 512);
    transpose_cast_kernel<<<dim3(16, 64), dim3(32, 8), 0, stream>>>(Wv, WqkvT + 2560 * 2048, 2048, 512);
    transpose_cast_kernel<<<dim3(64, 64), dim3(32, 8), 0, stream>>>(Wo, WoT, 2048, 2048);
    concat_bias_kernel<<<12, 256, 0, stream>>>(bq, bk, bv, qbias);

    gemm_kernel<true><<<dim3(24, 32), 256, 0, stream>>>(xb, WqkvT, qbias, QKV, M_, NQKV_, D_);
    transpose_v_kernel<<<dim3(4, 64, 8), dim3(32, 8), 0, stream>>>(QKV, Vt);
    attn_kernel<<<512, 256, 0, stream>>>(QKV, Vt, Cb);
    gemm_kernel<false><<<dim3(16, 32), 256, 0, stream>>>(Cb, WoT, bo, Yb, M_, D_, 2048);
    ln_kernel<<<M_, 256, 0, stream>>>(Yb, x, gamma, beta, out);
}

// Round 5
// 394.002 us; speedup vs baseline: 1.4645x; 1.0752x over previous
//
#include <hip/hip_runtime.h>
#include <hip/hip_bf16.h>
#include <math.h>

typedef __bf16 bf16_t;
typedef __bf16 bf16x4 __attribute__((ext_vector_type(4)));
typedef __bf16 bf16x8 __attribute__((ext_vector_type(8)));
typedef float  f32x4  __attribute__((ext_vector_type(4)));
typedef float  f32x16 __attribute__((ext_vector_type(16)));

#define MFMA16(a,b,c) __builtin_amdgcn_mfma_f32_16x16x32_bf16((a),(b),(c),0,0,0)
#define MFMA32(a,b,c) __builtin_amdgcn_mfma_f32_32x32x16_bf16((a),(b),(c),0,0,0)

// Problem constants
#define B_ 2
#define L_ 2048
#define D_ 2048
#define H_ 16
#define KV_ 4
#define E_ 128
#define M_ (B_*L_)      // 4096 rows
#define NQKV_ 3072      // H*E + 2*KV*E

// async global->LDS 16B (m97 pattern; LDS dest is wave-uniform base + lane*16)
__device__ __forceinline__ void async_ld16(const bf16_t* g, bf16_t* l) {
    __builtin_amdgcn_global_load_lds((const __attribute__((address_space(1))) void*)g,
                                     (__attribute__((address_space(3))) void*)l, 16, 0, 0);
}

// ---------------------------------------- cast x -> bf16, plus qkv bias concat tail blocks
__global__ __launch_bounds__(256) void cast_bias_kernel(const float* __restrict__ src,
                                                        bf16_t* __restrict__ dst,
                                                        const float* __restrict__ bq,
                                                        const float* __restrict__ bk,
                                                        const float* __restrict__ bv,
                                                        float* __restrict__ qbias) {
    int bid = blockIdx.x;
    if (bid < 8192) {
        int i = (bid * 256 + threadIdx.x) * 4;
        float4 v = *(const float4*)(src + i);
        bf16x4 o;
        o.x = (bf16_t)v.x; o.y = (bf16_t)v.y; o.z = (bf16_t)v.z; o.w = (bf16_t)v.w;
        *(bf16x4*)(dst + i) = o;
    } else {
        int i = (bid - 8192) * 256 + threadIdx.x;
        if (i < 2048) qbias[i] = bq[i];
        else if (i < 2560) qbias[i] = bk[i - 2048];
        else if (i < 3072) qbias[i] = bv[i - 2560];
    }
}

// -------------------- merged transpose+cast of Wq/Wk/Wv/Wo: W[K,N] f32 -> WT[N,K] bf16
__global__ __launch_bounds__(256) void wtrans_kernel(const float* __restrict__ Wq,
                                                     const float* __restrict__ Wk,
                                                     const float* __restrict__ Wv,
                                                     const float* __restrict__ Wo,
                                                     bf16_t* __restrict__ WqkvT,
                                                     bf16_t* __restrict__ WoT) {
    __shared__ float tile[32][33];
    int bx = blockIdx.x;
    const float* W; bf16_t* WT; int N, n0;
    if (bx < 64)      { W = Wq; WT = WqkvT;                  N = 2048; n0 = bx * 32; }
    else if (bx < 80) { W = Wk; WT = WqkvT + 2048 * 2048;    N = 512;  n0 = (bx - 64) * 32; }
    else if (bx < 96) { W = Wv; WT = WqkvT + 2560 * 2048;    N = 512;  n0 = (bx - 80) * 32; }
    else              { W = Wo; WT = WoT;                    N = 2048; n0 = (bx - 96) * 32; }
    int k0 = blockIdx.y * 32;
    int tx = threadIdx.x, ty = threadIdx.y;  // 32 x 8
    #pragma unroll
    for (int i = 0; i < 32; i += 8)
        tile[ty + i][tx] = W[(size_t)(k0 + ty + i) * N + n0 + tx];
    __syncthreads();
    #pragma unroll
    for (int i = 0; i < 32; i += 8)
        WT[(size_t)(n0 + ty + i) * 2048 + k0 + tx] = (bf16_t)tile[tx][ty + i];
}

// -------------------------------- V transpose: QKV[b,l,2560+kv*128+e] -> Vt[(b*4+kv)*128+e][l]
__global__ __launch_bounds__(256) void transpose_v_kernel(const bf16_t* __restrict__ QKV,
                                                          bf16_t* __restrict__ Vt) {
    __shared__ bf16_t tile[32][33];
    int e0 = blockIdx.x * 32, l0 = blockIdx.y * 32;
    int bk = blockIdx.z;                    // b*4 + kv
    int b = bk >> 2, kv = bk & 3;
    int tx = threadIdx.x, ty = threadIdx.y; // 32 x 8
    #pragma unroll
    for (int i = 0; i < 32; i += 8)
        tile[ty + i][tx] = QKV[(size_t)(b * L_ + l0 + ty + i) * NQKV_ + 2560 + kv * 128 + e0 + tx];
    __syncthreads();
    #pragma unroll
    for (int i = 0; i < 32; i += 8)
        Vt[((size_t)bk * 128 + e0 + ty + i) * L_ + l0 + tx] = tile[tx][ty + i];
}

// ---------------------------------------------------------------- bf16 MFMA GEMM
// C[M,N] = A[M,K] @ BT[N,K]^T + bias ; 128x128 tile, 4 waves, 4x4 16x16x32 MFMAs/wave
// staging via global_load_lds width 16 (m97). Optional fused exact-erf GELU epilogue.
template <bool OUT_BF16, bool GELU>
__global__ __launch_bounds__(256) void gemm_kernel(const bf16_t* __restrict__ A,
                                                   const bf16_t* __restrict__ BT,
                                                   const float* __restrict__ bias,
                                                   void* __restrict__ C,
                                                   int M, int N, int K) {
    __shared__ __align__(16) bf16_t sA[128][32];
    __shared__ __align__(16) bf16_t sB[128][32];
    int tid = threadIdx.x;
    int wave = tid >> 6, lane = tid & 63;
    int l16 = lane & 15, quad = lane >> 4;
    int row0 = blockIdx.y * 128;
    int col0 = blockIdx.x * 128;
    int wm = (wave >> 1) * 64;
    int wn = (wave & 1) * 64;

    f32x4 acc[4][4];
    #pragma unroll
    for (int i = 0; i < 4; ++i)
        #pragma unroll
        for (int j = 0; j < 4; ++j)
            acc[i][j] = f32x4{0.f, 0.f, 0.f, 0.f};

    for (int k0 = 0; k0 < K; k0 += 32) {
        #pragma unroll
        for (int c = 0; c < 2; ++c) {
            int lin = (c * 256 + tid) * 8;
            int r = lin >> 5, col = lin & 31;
            async_ld16(&A[(size_t)(row0 + r) * K + k0 + col], &sA[r][col]);
            async_ld16(&BT[(size_t)(col0 + r) * K + k0 + col], &sB[r][col]);
        }
        __syncthreads();
        bf16x8 af[4], bf[4];
        #pragma unroll
        for (int mt = 0; mt < 4; ++mt) af[mt] = *(const bf16x8*)&sA[wm + mt * 16 + l16][quad * 8];
        #pragma unroll
        for (int nt = 0; nt < 4; ++nt) bf[nt] = *(const bf16x8*)&sB[wn + nt * 16 + l16][quad * 8];
        #pragma unroll
        for (int mt = 0; mt < 4; ++mt)
            #pragma unroll
            for (int nt = 0; nt < 4; ++nt)
                acc[mt][nt] = MFMA16(af[mt], bf[nt], acc[mt][nt]);
        __syncthreads();
    }

    #pragma unroll
    for (int mt = 0; mt < 4; ++mt) {
        #pragma unroll
        for (int nt = 0; nt < 4; ++nt) {
            int gcol = col0 + wn + nt * 16 + l16;
            float bv = bias[gcol];
            #pragma unroll
            for (int r = 0; r < 4; ++r) {
                int grow = row0 + wm + mt * 16 + quad * 4 + r;
                float v = acc[mt][nt][r] + bv;
                if (GELU) v = 0.5f * v * (1.f + erff(v * 0.70710678118654752f));
                if (OUT_BF16) ((bf16_t*)C)[(size_t)grow * N + gcol] = (bf16_t)v;
                else          ((float*)C)[(size_t)grow * N + gcol] = v;
            }
        }
    }
}

// ---------------------------------------------------------------- flash attention (causal GQA)
// S^T = K@Q^T, ctx^T = V^T@P. Block = 256 = 2 units x 2 waves; unit 0: q-tile `pair`,
// unit 1: q-tile `31-pair`; shared double-buffered K/V staging (64 KiB LDS, XOR-swizzled
// 16B chunks), 1 barrier/iter, prefetch tile kt+1 into regs during compute of kt.
// P C-layout -> B-layout done in-register (q=lane&31 in both): half-swap via shfl_xor(32).
__global__ __launch_bounds__(256) void attn_kernel(const bf16_t* __restrict__ QKV,
                                                   const bf16_t* __restrict__ Vt,
                                                   bf16_t* __restrict__ Ctx) {
    __shared__ __align__(16) bf16_t sK[2][64][128];    // [buf][kpos][e], chunk ^= kpos&15
    __shared__ __align__(16) bf16_t sV[2][128][64];    // [buf][e][kpos], chunk ^= e&7

    const int tid = threadIdx.x;
    const int wave = tid >> 6, lane = tid & 63;
    const int unit = wave >> 1, wv = wave & 1;
    const int l31 = lane & 31, half = lane >> 5;
    const int pair = blockIdx.x & 15;
    const int h = (blockIdx.x >> 4) & 15;
    const int b = blockIdx.x >> 8;
    const int kv = h & 3;

    const bf16_t* Kbase = QKV + (size_t)b * L_ * NQKV_ + 2048 + kv * 128;
    const bf16_t* Vbase = Vt + (size_t)(b * 4 + kv) * 128 * L_;
    const float scale = 0.08838834764831845f; // 1/sqrt(128)

    const int t_u = unit ? 31 - pair : pair;   // this unit's q-tile
    const int ktmax = 31 - pair;               // block iterates 0..ktmax
    const int qrow = t_u * 64 + wv * 32 + l31; // this lane's q row

    // Q fragments (B-operand: n=q=l31, k=e)
    bf16x8 qf[8];
    const bf16_t* Qrow = QKV + (size_t)(b * L_ + qrow) * NQKV_ + h * 128 + half * 8;
    #pragma unroll
    for (int et = 0; et < 8; ++et) qf[et] = *(const bf16x8*)&Qrow[et * 16];

    f32x16 acc[4];
    #pragma unroll
    for (int em = 0; em < 4; ++em)
        #pragma unroll
        for (int j = 0; j < 16; ++j) acc[em][j] = 0.f;
    float m_i = -3.0e38f, l_i = 0.f;

    // per-thread staging chunks (4 sK + 4 sV b128 each)
    bf16x8 kreg[4], vreg[4];
    #define LOAD_TILE(KT)                                                            \
        {                                                                            \
            int kk = (KT) * 64;                                                      \
            _Pragma("unroll")                                                        \
            for (int p = 0; p < 4; ++p) {                                            \
                int ch = p * 256 + tid;                                              \
                int rk = ch >> 4, ck = ch & 15;                                      \
                kreg[p] = *(const bf16x8*)&Kbase[(size_t)(kk + rk) * NQKV_ + ck * 8];\
                int rv = ch >> 3, cv = ch & 7;                                       \
                vreg[p] = *(const bf16x8*)&Vbase[(size_t)rv * L_ + kk + cv * 8];     \
            }                                                                        \
        }

    LOAD_TILE(0);

    for (int kt = 0; kt <= ktmax; ++kt) {
        const int bufi = kt & 1;
        // ds_write prefetched tile (swizzled dest)
        #pragma unroll
        for (int p = 0; p < 4; ++p) {
            int ch = p * 256 + tid;
            int rk = ch >> 4, ck = ch & 15;
            *(bf16x8*)&sK[bufi][rk][(ck ^ (rk & 15)) * 8] = kreg[p];
            int rv = ch >> 3, cv = ch & 7;
            *(bf16x8*)&sV[bufi][rv][(cv ^ (rv & 7)) * 8] = vreg[p];
        }
        __syncthreads();
        if (kt < ktmax) LOAD_TILE(kt + 1);   // prefetch; lands during compute

        if (kt <= t_u) {
            // S^T[kpos][q] = K @ Q^T  (2 kpos-mtiles x 8 e-ktiles)
            f32x16 s[2];
            #pragma unroll
            for (int mt = 0; mt < 2; ++mt)
                #pragma unroll
                for (int j = 0; j < 16; ++j) s[mt][j] = 0.f;
            #pragma unroll
            for (int mt = 0; mt < 2; ++mt)
                #pragma unroll
                for (int et = 0; et < 8; ++et) {
                    bf16x8 kf = *(const bf16x8*)&sK[bufi][mt * 32 + l31][((et * 2 + half) ^ (l31 & 15)) * 8];
                    s[mt] = MFMA32(kf, qf[et], s[mt]);
                }

            #pragma unroll
            for (int mt = 0; mt < 2; ++mt)
                #pragma unroll
                for (int j = 0; j < 16; ++j) s[mt][j] *= scale;

            // causal mask on the diagonal tile (kpos row = (j&3)+8*(j>>2)+4*half)
            if (kt == t_u) {
                #pragma unroll
                for (int mt = 0; mt < 2; ++mt)
                    #pragma unroll
                    for (int j = 0; j < 16; ++j) {
                        int kidx = kt * 64 + mt * 32 + (j & 3) + 8 * (j >> 2) + 4 * half;
                        if (kidx > qrow) s[mt][j] = -3.0e38f;
                    }
            }

            // online softmax: in-register reduce over 32 kpos + one shfl_xor(32)
            float mx = s[0][0];
            #pragma unroll
            for (int mt = 0; mt < 2; ++mt)
                #pragma unroll
                for (int j = 0; j < 16; ++j) mx = fmaxf(mx, s[mt][j]);
            mx = fmaxf(mx, __shfl_xor(mx, 32, 64));
            float mnew = fmaxf(m_i, mx);
            float alpha = __expf(m_i - mnew);
            float rs = 0.f;
            #pragma unroll
            for (int mt = 0; mt < 2; ++mt)
                #pragma unroll
                for (int j = 0; j < 16; ++j) {
                    float p = __expf(s[mt][j] - mnew);
                    s[mt][j] = p;
                    rs += p;
                }
            rs += __shfl_xor(rs, 32, 64);
            l_i = l_i * alpha + rs;
            m_i = mnew;
            #pragma unroll
            for (int em = 0; em < 4; ++em)
                #pragma unroll
                for (int j = 0; j < 16; ++j) acc[em][j] *= alpha;

            // pack P to bf16 groups: pk[mt][g] holds kpos = 32mt+8g+4*half+(0..3), q=l31
            bf16x4 pk[2][4];
            #pragma unroll
            for (int mt = 0; mt < 2; ++mt)
                #pragma unroll
                for (int g = 0; g < 4; ++g) {
                    bf16x4 t;
                    #pragma unroll
                    for (int i = 0; i < 4; ++i) t[i] = (bf16_t)s[mt][g * 4 + i];
                    pk[mt][g] = t;
                }

            // ctx^T += V^T @ P : B-frag for k-chunk kc needs kpos 16kc+8*half+(0..7);
            // lower 4 live in half0 lanes, upper 4 in half1 -> one shfl_xor(32) half-swap.
            #pragma unroll
            for (int kc = 0; kc < 4; ++kc) {
                const int mts = kc >> 1, g0 = 2 * (kc & 1);
                bf16x4 send = half ? pk[mts][g0] : pk[mts][g0 + 1];
                bf16x4 keep = half ? pk[mts][g0 + 1] : pk[mts][g0];
                union { bf16x4 v; int i[2]; } su, ru;
                su.v = send;
                ru.i[0] = __shfl_xor(su.i[0], 32, 64);
                ru.i[1] = __shfl_xor(su.i[1], 32, 64);
                bf16x4 lo = half ? ru.v : keep;
                bf16x4 hi = half ? keep : ru.v;
                bf16x8 pf = __builtin_shufflevector(lo, hi, 0, 1, 2, 3, 4, 5, 6, 7);
                #pragma unroll
                for (int em = 0; em < 4; ++em) {
                    bf16x8 vf = *(const bf16x8*)&sV[bufi][em * 32 + l31][((kc * 2 + half) ^ (l31 & 7)) * 8];
                    acc[em] = MFMA32(vf, pf, acc[em]);
                }
            }
        }
    }

    // epilogue: ctx^T col=q=l31 -> per-lane row of Ctx; e contiguous in reg groups
    const float inv = 1.f / l_i;
    bf16_t* Cp = Ctx + (size_t)(b * L_ + qrow) * 2048 + h * 128;
    #pragma unroll
    for (int em = 0; em < 4; ++em)
        #pragma unroll
        for (int g = 0; g < 4; ++g) {
            bf16x4 ov;
            #pragma unroll
            for (int i = 0; i < 4; ++i) ov[i] = (bf16_t)(acc[em][g * 4 + i] * inv);
            *(bf16x4*)&Cp[em * 32 + g * 8 + half * 4] = ov;
        }
}

// ------------------------------------------ residual + LayerNorm (GELU already fused in GEMM)
__global__ __launch_bounds__(256) void ln_kernel(const bf16_t* __restrict__ Y,
                                                 const float* __restrict__ X,
                                                 const float* __restrict__ gamma,
                                                 const float* __restrict__ beta,
                                                 float* __restrict__ out) {
    __shared__ float sr[2048];
    __shared__ float wred[8];
    size_t row = blockIdx.x;
    const bf16_t* y = Y + row * 2048;
    const float* x = X + row * 2048;
    float sum = 0.f, ssq = 0.f;
    #pragma unroll
    for (int c = 0; c < 2; ++c) {
        int i = (c * 256 + threadIdx.x) * 4;
        bf16x4 yv = *(const bf16x4*)(y + i);
        float4 xv = *(const float4*)(x + i);
        float r0 = xv.x + (float)yv[0];
        float r1 = xv.y + (float)yv[1];
        float r2 = xv.z + (float)yv[2];
        float r3 = xv.w + (float)yv[3];
        sr[i] = r0; sr[i + 1] = r1; sr[i + 2] = r2; sr[i + 3] = r3;
        sum += r0 + r1 + r2 + r3;
        ssq += r0 * r0 + r1 * r1 + r2 * r2 + r3 * r3;
    }
    #pragma unroll
    for (int off = 32; off > 0; off >>= 1) {
        sum += __shfl_xor(sum, off, 64);
        ssq += __shfl_xor(ssq, off, 64);
    }
    int wv = threadIdx.x >> 6;
    if ((threadIdx.x & 63) == 0) { wred[wv] = sum; wred[wv + 4] = ssq; }
    __syncthreads();
    sum = wred[0] + wred[1] + wred[2] + wred[3];
    ssq = wred[4] + wred[5] + wred[6] + wred[7];
    float mu = sum * (1.f / 2048.f);
    float var = ssq * (1.f / 2048.f) - mu * mu;
    float rstd = rsqrtf(var + 1e-5f);
    #pragma unroll
    for (int c = 0; c < 2; ++c) {
        int i = (c * 256 + threadIdx.x) * 4;
        float4 gv = *(const float4*)(gamma + i);
        float4 bv = *(const float4*)(beta + i);
        float4 o;
        o.x = (sr[i]     - mu) * rstd * gv.x + bv.x;
        o.y = (sr[i + 1] - mu) * rstd * gv.y + bv.y;
        o.z = (sr[i + 2] - mu) * rstd * gv.z + bv.z;
        o.w = (sr[i + 3] - mu) * rstd * gv.w + bv.w;
        *(float4*)(out + row * 2048 + i) = o;
    }
}

// ----------------------------------------------------------------------------- launch
extern "C" void kernel_launch(void* const* d_in, const int* in_sizes, int n_in,
                              void* d_out, int out_size, void* d_ws, size_t ws_size,
                              hipStream_t stream) {
    const float* x     = (const float*)d_in[0];
    const float* Wq    = (const float*)d_in[1];
    const float* bq    = (const float*)d_in[2];
    const float* Wk    = (const float*)d_in[3];
    const float* bk    = (const float*)d_in[4];
    const float* Wv    = (const float*)d_in[5];
    const float* bv    = (const float*)d_in[6];
    const float* Wo    = (const float*)d_in[7];
    const float* bo    = (const float*)d_in[8];
    const float* gamma = (const float*)d_in[9];
    const float* beta  = (const float*)d_in[10];
    float* out = (float*)d_out;

    char* ws = (char*)d_ws;
    size_t off = 0;
    bf16_t* xb    = (bf16_t*)(ws + off); off += 16777216;   // 4096x2048 bf16
    bf16_t* WqkvT = (bf16_t*)(ws + off); off += 12582912;   // 3072x2048 bf16
    bf16_t* WoT   = (bf16_t*)(ws + off); off += 8388608;    // 2048x2048 bf16
    float*  qbias = (float*)(ws + off);  off += 12288;      // 3072 f32
    bf16_t* QKV   = (bf16_t*)(ws + off); off += 25165824;   // 4096x3072 bf16
    bf16_t* Vt    = (bf16_t*)(ws + off); off += 4194304;    // 8x128x2048 bf16
    bf16_t* Cb    = (bf16_t*)(ws + off); off += 16777216;   // 4096x2048 bf16
    bf16_t* Yb    = (bf16_t*)(ws + off); off += 16777216;   // 4096x2048 bf16 (GELU'd)

    cast_bias_kernel<<<8204, 256, 0, stream>>>(x, xb, bq, bk, bv, qbias);
    wtrans_kernel<<<dim3(160, 64), dim3(32, 8), 0, stream>>>(Wq, Wk, Wv, Wo, WqkvT, WoT);

    gemm_kernel<true, false><<<dim3(24, 32), 256, 0, stream>>>(xb, WqkvT, qbias, QKV, M_, NQKV_, D_);
    transpose_v_kernel<<<dim3(4, 64, 8), dim3(32, 8), 0, stream>>>(QKV, Vt);
    attn_kernel<<<512, 256, 0, stream>>>(QKV, Vt, Cb);
    gemm_kernel<true, true><<<dim3(16, 32), 256, 0, stream>>>(Cb, WoT, bo, Yb, M_, D_, 2048);
    ln_kernel<<<M_, 256, 0, stream>>>(Yb, x, gamma, beta, out);
}